// Round 1
// baseline (631.583 us; speedup 1.0000x reference)
//
#include <hip/hip_runtime.h>
#include <hip/hip_bf16.h>

// Problem constants
#define TSEQ   2048
#define NHEAD  16
#define DMODEL 1024

typedef __attribute__((ext_vector_type(8))) __bf16 bf16x8;
typedef __attribute__((ext_vector_type(4))) float  f32x4;

static __device__ __forceinline__ unsigned short f2bf(float f){
  union { float f; unsigned u; } v; v.f = f;
  return (unsigned short)((v.u + 0x7FFFu + ((v.u >> 16) & 1u)) >> 16);
}

static __device__ __forceinline__ f32x4 mfma16(bf16x8 a, bf16x8 b, f32x4 c){
  return __builtin_amdgcn_mfma_f32_16x16x32_bf16(a, b, c, 0, 0, 0);
}

// ---------------- cast x (f32 -> bf16), vectorized ----------------
__global__ __launch_bounds__(256) void cast_x_kernel(const float* __restrict__ in,
                                                     unsigned short* __restrict__ out){
  int i = blockIdx.x * 256 + threadIdx.x;
  float4 v = *(const float4*)(in + (size_t)i * 4);
  ushort4 o;
  o.x = f2bf(v.x); o.y = f2bf(v.y); o.z = f2bf(v.z); o.w = f2bf(v.w);
  *(ushort4*)(out + (size_t)i * 4) = o;
}

// -------- transpose + cast: in [K][N] f32  ->  out [N][K] bf16 --------
__global__ __launch_bounds__(256) void transpose_cast_kernel(const float* __restrict__ in,
                                                             unsigned short* __restrict__ out,
                                                             int K, int N){
  __shared__ float tile[32][33];
  int n0 = blockIdx.x * 32, k0 = blockIdx.y * 32;
  int tx = threadIdx.x & 31, ty = threadIdx.x >> 5;   // tx fast, ty 0..7
  #pragma unroll
  for (int r = ty; r < 32; r += 8)
    tile[r][tx] = in[(size_t)(k0 + r) * N + n0 + tx];
  __syncthreads();
  #pragma unroll
  for (int r = ty; r < 32; r += 8)
    out[(size_t)(n0 + r) * K + k0 + tx] = f2bf(tile[tx][r]);
}

// ---------------- bf16 MFMA GEMM: C = A[M][K] * Bt[N][K]^T + bias ----------------
// MODE 0: qkv projection -> scatter to q [B,H,T,64] (prescaled 1/8), k [B,H,T,64], vT [B,H,64,T]
// MODE 1: out projection -> fp32 out [M][N]
template<int MODE>
__global__ __launch_bounds__(256) void gemm_bf16_kernel(
    const unsigned short* __restrict__ A,
    const unsigned short* __restrict__ Bt,
    const float* __restrict__ bias,
    float* __restrict__ outF,
    unsigned short* __restrict__ qo,
    unsigned short* __restrict__ ko,
    unsigned short* __restrict__ vTo,
    int Kdim, int Ndim)
{
  __shared__ unsigned short As[64][40];  // +8 pad: row stride 80B (16B-aligned, spreads banks)
  __shared__ unsigned short Bs[64][40];
  const int n0 = blockIdx.x * 64, m0 = blockIdx.y * 64;
  const int tid = threadIdx.x;
  const int lane = tid & 63, w = tid >> 6;
  const int lrow = lane & 15, kseg = lane >> 4;
  const int srow = tid >> 2, schunk = (tid & 3) * 8;
  const unsigned short* Ap = A  + (size_t)(m0 + srow) * Kdim + schunk;
  const unsigned short* Bp = Bt + (size_t)(n0 + srow) * Kdim + schunk;

  f32x4 acc[4] = {};
  for (int kt = 0; kt < Kdim; kt += 32){
    *(bf16x8*)&As[srow][schunk] = *(const bf16x8*)(Ap + kt);
    *(bf16x8*)&Bs[srow][schunk] = *(const bf16x8*)(Bp + kt);
    __syncthreads();
    bf16x8 a = *(const bf16x8*)&As[16*w + lrow][kseg*8];
    #pragma unroll
    for (int f = 0; f < 4; ++f){
      bf16x8 b = *(const bf16x8*)&Bs[16*f + lrow][kseg*8];
      acc[f] = mfma16(a, b, acc[f]);
    }
    __syncthreads();
  }

  #pragma unroll
  for (int f = 0; f < 4; ++f){
    int gc = n0 + 16*f + lrow;
    float bv = bias[gc];
    #pragma unroll
    for (int r = 0; r < 4; ++r){
      int gr = m0 + 16*w + 4*kseg + r;           // C/D layout: row=(lane>>4)*4+reg, col=lane&15
      float val = acc[f][r] + bv;
      if (MODE == 1){
        outF[(size_t)gr * Ndim + gc] = val;
      } else {
        int b = gr >> 11, t = gr & (TSEQ - 1);
        if (gc < DMODEL){
          int h = gc >> 6, d = gc & 63;
          qo[(((size_t)b*NHEAD + h)*TSEQ + t)*64 + d] = f2bf(val * 0.125f);  // fold scale (exact pow2)
        } else if (gc < 2*DMODEL){
          int c = gc - DMODEL, h = c >> 6, d = c & 63;
          ko[(((size_t)b*NHEAD + h)*TSEQ + t)*64 + d] = f2bf(val);
        } else {
          int c = gc - 2*DMODEL, h = c >> 6, d = c & 63;
          vTo[(((size_t)b*NHEAD + h)*64 + d)*TSEQ + t] = f2bf(val);
        }
      }
    }
  }
}

// ---------------- causal flash attention ----------------
// block = 4 waves; each wave owns 16 q-rows; block covers 64 q-rows of one (b,h).
__global__ __launch_bounds__(256) void attn_kernel(
    const unsigned short* __restrict__ q,   // [BH][T][64], pre-scaled by 1/8
    const unsigned short* __restrict__ k,   // [BH][T][64]
    const unsigned short* __restrict__ vT,  // [BH][64][T]
    unsigned short* __restrict__ y)         // [B*T][1024] bf16
{
  __shared__ unsigned short Pl[4][16][72];  // per-wave P transpose buffer (row stride 144B)
  const int qt = blockIdx.x;    // q tile (64 rows)
  const int bh = blockIdx.y;    // b*16+h
  const int tid = threadIdx.x;
  const int lane = tid & 63, w = tid >> 6;
  const int lrow = lane & 15, kseg = lane >> 4;
  const int qr0 = qt * 64 + w * 16;

  const unsigned short* qp = q + ((size_t)bh * TSEQ + qr0 + lrow) * 64 + kseg * 8;
  bf16x8 aq0 = *(const bf16x8*)qp;
  bf16x8 aq1 = *(const bf16x8*)(qp + 32);

  f32x4 o[4] = {};
  float mrun[4] = {-1e30f, -1e30f, -1e30f, -1e30f};
  float lrun[4] = {0.f, 0.f, 0.f, 0.f};

  for (int kb = 0; kb <= qt; ++kb){
    const int kt0 = kb * 64;
    // ---- S = Q K^T (keys = 16f + lrow, q rows = 4*kseg + r) ----
    f32x4 s[4];
    #pragma unroll
    for (int f = 0; f < 4; ++f){
      const unsigned short* kp = k + ((size_t)bh * TSEQ + kt0 + 16*f + lrow) * 64 + kseg * 8;
      bf16x8 b0 = *(const bf16x8*)kp;
      bf16x8 b1 = *(const bf16x8*)(kp + 32);
      f32x4 acc = {0.f, 0.f, 0.f, 0.f};
      acc = mfma16(aq0, b0, acc);
      acc = mfma16(aq1, b1, acc);
      s[f] = acc;
    }
    // ---- causal mask (only the diagonal tile needs it) ----
    if (kb == qt){
      #pragma unroll
      for (int f = 0; f < 4; ++f){
        int key = kt0 + 16*f + lrow;
        #pragma unroll
        for (int r = 0; r < 4; ++r){
          int qrow = qr0 + 4*kseg + r;
          if (key > qrow) s[f][r] = -1e30f;
        }
      }
    }
    // ---- online softmax: reduce across the 16 lanes of each row-group ----
    #pragma unroll
    for (int r = 0; r < 4; ++r){
      float mx = fmaxf(fmaxf(s[0][r], s[1][r]), fmaxf(s[2][r], s[3][r]));
      mx = fmaxf(mx, __shfl_xor(mx, 1));
      mx = fmaxf(mx, __shfl_xor(mx, 2));
      mx = fmaxf(mx, __shfl_xor(mx, 4));
      mx = fmaxf(mx, __shfl_xor(mx, 8));
      float mnew = fmaxf(mrun[r], mx);
      float rescale = __expf(mrun[r] - mnew);
      mrun[r] = mnew;
      float sum = 0.f;
      #pragma unroll
      for (int f = 0; f < 4; ++f){
        float p = __expf(s[f][r] - mnew);
        s[f][r] = p;
        sum += p;
      }
      sum += __shfl_xor(sum, 1);
      sum += __shfl_xor(sum, 2);
      sum += __shfl_xor(sum, 4);
      sum += __shfl_xor(sum, 8);
      lrun[r] = lrun[r] * rescale + sum;
      #pragma unroll
      for (int g = 0; g < 4; ++g) o[g][r] = o[g][r] * rescale;
    }
    // ---- transpose P through per-wave LDS (score layout -> A-fragment layout) ----
    #pragma unroll
    for (int f = 0; f < 4; ++f)
      #pragma unroll
      for (int r = 0; r < 4; ++r)
        Pl[w][4*kseg + r][16*f + lrow] = f2bf(s[f][r]);
    const unsigned short* pp = &Pl[w][lrow][0];   // wave-local, compiler inserts lgkm waits
    bf16x8 pa0 = *(const bf16x8*)(pp + kseg*8);
    bf16x8 pa1 = *(const bf16x8*)(pp + 32 + kseg*8);
    // ---- O += P V  (V^T rows are contiguous in k) ----
    #pragma unroll
    for (int g = 0; g < 4; ++g){
      const unsigned short* vp = vT + ((size_t)bh * 64 + 16*g + lrow) * TSEQ + kt0 + kseg * 8;
      bf16x8 v0 = *(const bf16x8*)vp;
      bf16x8 v1 = *(const bf16x8*)(vp + 32);
      o[g] = mfma16(pa0, v0, o[g]);
      o[g] = mfma16(pa1, v1, o[g]);
    }
  }

  // ---- epilogue: y[b][t][h*64+d] = O / l ----
  const int b = bh >> 4, h = bh & (NHEAD - 1);
  #pragma unroll
  for (int g = 0; g < 4; ++g){
    #pragma unroll
    for (int r = 0; r < 4; ++r){
      int t = qr0 + 4*kseg + r;
      float val = o[g][r] / lrun[r];
      y[((size_t)b * TSEQ + t) * DMODEL + h * 64 + 16*g + lrow] = f2bf(val);
    }
  }
}

extern "C" void kernel_launch(void* const* d_in, const int* in_sizes, int n_in,
                              void* d_out, int out_size, void* d_ws, size_t ws_size,
                              hipStream_t stream) {
  const float* x    = (const float*)d_in[0];
  const float* Wqkv = (const float*)d_in[1];
  const float* bqkv = (const float*)d_in[2];
  const float* Wo   = (const float*)d_in[3];
  const float* bo   = (const float*)d_in[4];
  float* out = (float*)d_out;

  // Workspace layout (72 MB total):
  // [0,16M):   x_bf (later reused as y_bf — x_bf dead after GEMM1)
  // [16,22M):  Wqkv^T bf16   [22,24M): Wo^T bf16
  // [24,40M):  q   [40,56M): k   [56,72M): vT
  char* ws = (char*)d_ws;
  unsigned short* x_bf   = (unsigned short*)(ws);
  unsigned short* Wqkv_t = (unsigned short*)(ws + (16u << 20));
  unsigned short* Wo_t   = (unsigned short*)(ws + (22u << 20));
  unsigned short* q_ws   = (unsigned short*)(ws + (24u << 20));
  unsigned short* k_ws   = (unsigned short*)(ws + (40u << 20));
  unsigned short* vT_ws  = (unsigned short*)(ws + (56u << 20));
  unsigned short* y_bf   = x_bf;

  cast_x_kernel<<<8192, 256, 0, stream>>>(x, x_bf);                                   // 8.39M elems
  transpose_cast_kernel<<<dim3(96, 32), 256, 0, stream>>>(Wqkv, Wqkv_t, 1024, 3072);
  transpose_cast_kernel<<<dim3(32, 32), 256, 0, stream>>>(Wo, Wo_t, 1024, 1024);

  gemm_bf16_kernel<0><<<dim3(48, 128), 256, 0, stream>>>(x_bf, Wqkv_t, bqkv,
                                                         nullptr, q_ws, k_ws, vT_ws, 1024, 3072);
  attn_kernel<<<dim3(32, 64), 256, 0, stream>>>(q_ws, k_ws, vT_ws, y_bf);
  gemm_bf16_kernel<1><<<dim3(16, 128), 256, 0, stream>>>(y_bf, Wo_t, bo,
                                                         out, nullptr, nullptr, nullptr, 1024, 1024);
}

// Round 2
// 283.260 us; speedup vs baseline: 2.2297x; 2.2297x over previous
//
#include <hip/hip_runtime.h>
#include <hip/hip_bf16.h>

// Problem constants
#define TSEQ   2048
#define NHEAD  16
#define DMODEL 1024

typedef __attribute__((ext_vector_type(8))) __bf16 bf16x8;
typedef __attribute__((ext_vector_type(4))) float  f32x4;

typedef const void __attribute__((address_space(1))) * gptr_as1;
typedef void       __attribute__((address_space(3))) * lptr_as3;

static __device__ __forceinline__ void gload_lds16(const void* g, void* l){
  // async global->LDS, 16B per lane; LDS dest = wave-uniform base + lane*16
  __builtin_amdgcn_global_load_lds((gptr_as1)g, (lptr_as3)l, 16, 0, 0);
}

static __device__ __forceinline__ unsigned short f2bf(float f){
  union { float f; unsigned u; } v; v.f = f;
  return (unsigned short)((v.u + 0x7FFFu + ((v.u >> 16) & 1u)) >> 16);
}

static __device__ __forceinline__ f32x4 mfma16(bf16x8 a, bf16x8 b, f32x4 c){
  return __builtin_amdgcn_mfma_f32_16x16x32_bf16(a, b, c, 0, 0, 0);
}

// ---------------- cast x (f32 -> bf16), vectorized ----------------
__global__ __launch_bounds__(256) void cast_x_kernel(const float* __restrict__ in,
                                                     unsigned short* __restrict__ out){
  int i = blockIdx.x * 256 + threadIdx.x;
  float4 v = *(const float4*)(in + (size_t)i * 4);
  ushort4 o;
  o.x = f2bf(v.x); o.y = f2bf(v.y); o.z = f2bf(v.z); o.w = f2bf(v.w);
  *(ushort4*)(out + (size_t)i * 4) = o;
}

// -------- transpose + cast: in [K][N] f32  ->  out [N][K] bf16 --------
__global__ __launch_bounds__(256) void transpose_cast_kernel(const float* __restrict__ in,
                                                             unsigned short* __restrict__ out,
                                                             int K, int N){
  __shared__ float tile[32][33];
  int n0 = blockIdx.x * 32, k0 = blockIdx.y * 32;
  int tx = threadIdx.x & 31, ty = threadIdx.x >> 5;
  #pragma unroll
  for (int r = ty; r < 32; r += 8)
    tile[r][tx] = in[(size_t)(k0 + r) * N + n0 + tx];
  __syncthreads();
  #pragma unroll
  for (int r = ty; r < 32; r += 8)
    out[(size_t)(n0 + r) * K + k0 + tx] = f2bf(tile[tx][r]);
}

// ---------------- bf16 MFMA GEMM (m97 structure): C = A[M][K] * Bt[N][K]^T + bias ----
// 128x128 tile, 4 waves (2x2), BK=32, global_load_lds staging with (row&3) src swizzle.
// MODE 0: qkv projection -> scatter q [B,H,T,64] (prescaled 1/8), k [B,H,T,64], vT [B,H,64,T]
// MODE 1: out projection -> fp32 out [M][N]
template<int MODE>
__global__ __launch_bounds__(256) void gemm_bf16_kernel(
    const unsigned short* __restrict__ A,
    const unsigned short* __restrict__ Bt,
    const float* __restrict__ bias,
    float* __restrict__ outF,
    unsigned short* __restrict__ qo,
    unsigned short* __restrict__ ko,
    unsigned short* __restrict__ vTo,
    int Kdim, int Ndim)
{
  __shared__ unsigned short As[128 * 32];   // [128][32], linear (gload_lds needs linear dest)
  __shared__ unsigned short Bs[128 * 32];

  // bijective XCD swizzle (nwg % 8 == 0 for all our grids)
  const int nwg  = gridDim.x * gridDim.y;
  const int orig = blockIdx.y * gridDim.x + blockIdx.x;
  const int swz  = (orig & 7) * (nwg >> 3) + (orig >> 3);
  const int n0 = (swz % gridDim.x) * 128;
  const int m0 = (swz / gridDim.x) * 128;

  const int tid = threadIdx.x, lane = tid & 63, w = tid >> 6;
  const int wm = w & 1, wn = w >> 1;
  const int lrow = lane & 15, kseg = lane >> 4;

  // staging geometry: one instr = 64 lanes x 16B = 1KB = 16 rows of 32 elems
  const int s16  = lane >> 2;     // row within 16-row slab
  const int sch  = lane & 3;      // 16B chunk within row

  f32x4 acc[4][4] = {};

  for (int kt = 0; kt < Kdim; kt += 32){
    #pragma unroll
    for (int j = 0; j < 2; ++j){
      const int idx = (w << 1) + j;            // 0..7
      const int row = (idx << 4) + s16;        // 0..127
      const int c4  = sch ^ (row & 3);         // pre-swizzled source chunk
      gload_lds16(A  + (size_t)(m0 + row) * Kdim + kt + c4 * 8, &As[idx * 512]);
      gload_lds16(Bt + (size_t)(n0 + row) * Kdim + kt + c4 * 8, &Bs[idx * 512]);
    }
    __syncthreads();   // compiler drains vmcnt before barrier -> staging complete

    bf16x8 af[4], bfr[4];
    #pragma unroll
    for (int mi = 0; mi < 4; ++mi){
      const int row = wm * 64 + mi * 16 + lrow;
      af[mi] = *(const bf16x8*)&As[row * 32 + ((kseg ^ (row & 3)) << 3)];
    }
    #pragma unroll
    for (int ni = 0; ni < 4; ++ni){
      const int row = wn * 64 + ni * 16 + lrow;
      bfr[ni] = *(const bf16x8*)&Bs[row * 32 + ((kseg ^ (row & 3)) << 3)];
    }
    #pragma unroll
    for (int mi = 0; mi < 4; ++mi)
      #pragma unroll
      for (int ni = 0; ni < 4; ++ni)
        acc[mi][ni] = mfma16(af[mi], bfr[ni], acc[mi][ni]);
    __syncthreads();
  }

  // epilogue: C/D layout col=lane&15, row=(lane>>4)*4+reg
  #pragma unroll
  for (int ni = 0; ni < 4; ++ni){
    const int gc = n0 + wn * 64 + ni * 16 + lrow;
    const float bv = bias[gc];
    #pragma unroll
    for (int mi = 0; mi < 4; ++mi){
      #pragma unroll
      for (int r_ = 0; r_ < 4; ++r_){
        const int gr = m0 + wm * 64 + mi * 16 + (kseg << 2) + r_;
        float val = acc[mi][ni][r_] + bv;
        if (MODE == 1){
          outF[(size_t)gr * Ndim + gc] = val;
        } else {
          const int bb = gr >> 11, t = gr & (TSEQ - 1);
          if (gc < DMODEL){
            const int h = gc >> 6, d = gc & 63;
            qo[(((size_t)bb * NHEAD + h) * TSEQ + t) * 64 + d] = f2bf(val * 0.125f);
          } else if (gc < 2 * DMODEL){
            const int c = gc - DMODEL, h = c >> 6, d = c & 63;
            ko[(((size_t)bb * NHEAD + h) * TSEQ + t) * 64 + d] = f2bf(val);
          } else {
            const int c = gc - 2 * DMODEL, h = c >> 6, d = c & 63;
            vTo[(((size_t)bb * NHEAD + h) * 64 + d) * TSEQ + t] = f2bf(val);
          }
        }
      }
    }
  }
}

// ---------------- causal flash attention ----------------
// Block = 4 waves = 64 q-rows per tile; each block does q-tiles {p, 31-p} -> uniform 33 k-iters.
// K,V staged in LDS via global_load_lds (shared by all 4 waves), XOR source pre-swizzle.
__global__ __launch_bounds__(256) void attn_kernel(
    const unsigned short* __restrict__ qg,   // [BH][T][64], pre-scaled by 1/8
    const unsigned short* __restrict__ kg,   // [BH][T][64]
    const unsigned short* __restrict__ vTg,  // [BH][64][T]
    unsigned short* __restrict__ y)          // [B*T][1024] bf16
{
  __shared__ unsigned short Ks[64 * 64];     // [key r][d], swizzled: lds chunk c holds src chunk c^(r&7)
  __shared__ unsigned short Vs[64 * 64];     // [d r][key], same swizzle
  __shared__ unsigned short Pl[4][16][72];   // per-wave P transpose

  const int nwg  = gridDim.x * gridDim.y;    // 1024
  const int orig = blockIdx.y * gridDim.x + blockIdx.x;
  const int swz  = (orig & 7) * (nwg >> 3) + (orig >> 3);
  const int p  = swz & 15;                   // pair index 0..15
  const int bh = swz >> 4;                   // 0..63 (each XCD gets 8 consecutive bh)

  const int tid = threadIdx.x, lane = tid & 63, w = tid >> 6;
  const int lrow = lane & 15, kseg = lane >> 4;
  const int bb = bh >> 4, h = bh & (NHEAD - 1);

  // staging geometry: one instr = 1KB = 8 rows of 128B (64 bf16)
  const int sr8 = lane >> 3;                 // row within 8-row slab
  const int sc8 = lane & 7;                  // 16B chunk within row

  for (int hf = 0; hf < 2; ++hf){
    const int qt  = hf ? (31 - p) : p;
    const int qr0 = qt * 64 + w * 16;

    const unsigned short* qp = qg + ((size_t)bh * TSEQ + qr0 + lrow) * 64 + kseg * 8;
    bf16x8 aq0 = *(const bf16x8*)qp;
    bf16x8 aq1 = *(const bf16x8*)(qp + 32);

    f32x4 o[4] = {};
    float mrun[4] = {-1e30f, -1e30f, -1e30f, -1e30f};
    float lrun[4] = {0.f, 0.f, 0.f, 0.f};

    for (int kb = 0; kb <= qt; ++kb){
      const int kt0 = kb * 64;
      // ---- stage K,V tiles (all 4 waves cooperate; 8+8 instrs total) ----
      #pragma unroll
      for (int j = 0; j < 2; ++j){
        const int idx = (w << 1) + j;          // 0..7
        const int r   = (idx << 3) + sr8;      // 0..63
        const int c8  = sc8 ^ (r & 7);         // pre-swizzled source chunk
        gload_lds16(kg  + ((size_t)bh * TSEQ + kt0 + r) * 64 + c8 * 8, &Ks[idx * 512]);
        gload_lds16(vTg + ((size_t)bh * 64 + r) * TSEQ + kt0 + c8 * 8, &Vs[idx * 512]);
      }
      __syncthreads();

      // ---- S = Q K^T ----
      f32x4 s[4];
      #pragma unroll
      for (int f = 0; f < 4; ++f){
        const int kr = 16 * f + lrow, sw = kr & 7;
        bf16x8 b0 = *(const bf16x8*)&Ks[kr * 64 + ((kseg       ^ sw) << 3)];
        bf16x8 b1 = *(const bf16x8*)&Ks[kr * 64 + (((kseg + 4) ^ sw) << 3)];
        f32x4 a = {0.f, 0.f, 0.f, 0.f};
        a = mfma16(aq0, b0, a);
        a = mfma16(aq1, b1, a);
        s[f] = a;
      }
      // ---- causal mask (diagonal tile only) ----
      if (kb == qt){
        #pragma unroll
        for (int f = 0; f < 4; ++f){
          const int key = kt0 + 16 * f + lrow;
          #pragma unroll
          for (int r_ = 0; r_ < 4; ++r_){
            const int qrow = qr0 + 4 * kseg + r_;
            if (key > qrow) s[f][r_] = -1e30f;
          }
        }
      }
      // ---- online softmax (16-lane row groups) ----
      #pragma unroll
      for (int r_ = 0; r_ < 4; ++r_){
        float mx = fmaxf(fmaxf(s[0][r_], s[1][r_]), fmaxf(s[2][r_], s[3][r_]));
        mx = fmaxf(mx, __shfl_xor(mx, 1));
        mx = fmaxf(mx, __shfl_xor(mx, 2));
        mx = fmaxf(mx, __shfl_xor(mx, 4));
        mx = fmaxf(mx, __shfl_xor(mx, 8));
        const float mnew = fmaxf(mrun[r_], mx);
        const float rescale = __expf(mrun[r_] - mnew);
        mrun[r_] = mnew;
        float sum = 0.f;
        #pragma unroll
        for (int f = 0; f < 4; ++f){
          const float pv = __expf(s[f][r_] - mnew);
          s[f][r_] = pv;
          sum += pv;
        }
        sum += __shfl_xor(sum, 1);
        sum += __shfl_xor(sum, 2);
        sum += __shfl_xor(sum, 4);
        sum += __shfl_xor(sum, 8);
        lrun[r_] = lrun[r_] * rescale + sum;
        #pragma unroll
        for (int g = 0; g < 4; ++g) o[g][r_] *= rescale;
      }
      // ---- transpose P through per-wave LDS ----
      #pragma unroll
      for (int f = 0; f < 4; ++f)
        #pragma unroll
        for (int r_ = 0; r_ < 4; ++r_)
          Pl[w][4 * kseg + r_][16 * f + lrow] = f2bf(s[f][r_]);
      const unsigned short* pp = &Pl[w][lrow][0];
      bf16x8 pa0 = *(const bf16x8*)(pp + kseg * 8);
      bf16x8 pa1 = *(const bf16x8*)(pp + 32 + kseg * 8);
      // ---- O += P V ----
      #pragma unroll
      for (int g = 0; g < 4; ++g){
        const int vr = 16 * g + lrow, sw = vr & 7;
        bf16x8 v0 = *(const bf16x8*)&Vs[vr * 64 + ((kseg       ^ sw) << 3)];
        bf16x8 v1 = *(const bf16x8*)&Vs[vr * 64 + (((kseg + 4) ^ sw) << 3)];
        o[g] = mfma16(pa0, v0, o[g]);
        o[g] = mfma16(pa1, v1, o[g]);
      }
      __syncthreads();   // all waves done with Ks/Vs before restage
    }

    // ---- epilogue ----
    #pragma unroll
    for (int g = 0; g < 4; ++g){
      #pragma unroll
      for (int r_ = 0; r_ < 4; ++r_){
        const int t = qr0 + 4 * kseg + r_;
        y[((size_t)bb * TSEQ + t) * DMODEL + h * 64 + 16 * g + lrow] = f2bf(o[g][r_] / lrun[r_]);
      }
    }
  }
}

extern "C" void kernel_launch(void* const* d_in, const int* in_sizes, int n_in,
                              void* d_out, int out_size, void* d_ws, size_t ws_size,
                              hipStream_t stream) {
  const float* x    = (const float*)d_in[0];
  const float* Wqkv = (const float*)d_in[1];
  const float* bqkv = (const float*)d_in[2];
  const float* Wo   = (const float*)d_in[3];
  const float* bo   = (const float*)d_in[4];
  float* out = (float*)d_out;

  char* ws = (char*)d_ws;
  unsigned short* x_bf   = (unsigned short*)(ws);
  unsigned short* Wqkv_t = (unsigned short*)(ws + (16u << 20));
  unsigned short* Wo_t   = (unsigned short*)(ws + (22u << 20));
  unsigned short* q_ws   = (unsigned short*)(ws + (24u << 20));
  unsigned short* k_ws   = (unsigned short*)(ws + (40u << 20));
  unsigned short* vT_ws  = (unsigned short*)(ws + (56u << 20));
  unsigned short* y_bf   = x_bf;   // x_bf dead after GEMM1

  cast_x_kernel<<<8192, 256, 0, stream>>>(x, x_bf);
  transpose_cast_kernel<<<dim3(96, 32), 256, 0, stream>>>(Wqkv, Wqkv_t, 1024, 3072);
  transpose_cast_kernel<<<dim3(32, 32), 256, 0, stream>>>(Wo, Wo_t, 1024, 1024);

  gemm_bf16_kernel<0><<<dim3(24, 64), 256, 0, stream>>>(x_bf, Wqkv_t, bqkv,
                                                        nullptr, q_ws, k_ws, vT_ws, 1024, 3072);
  attn_kernel<<<dim3(16, 64), 256, 0, stream>>>(q_ws, k_ws, vT_ws, y_bf);
  gemm_bf16_kernel<1><<<dim3(8, 64), 256, 0, stream>>>(y_bf, Wo_t, bo,
                                                       out, nullptr, nullptr, nullptr, 1024, 1024);
}

// Round 3
// 201.862 us; speedup vs baseline: 3.1288x; 1.4032x over previous
//
#include <hip/hip_runtime.h>
#include <hip/hip_bf16.h>

// Problem constants
#define TSEQ   2048
#define NHEAD  16
#define DMODEL 1024

typedef __attribute__((ext_vector_type(8)))  __bf16 bf16x8;
typedef __attribute__((ext_vector_type(4)))  float  f32x4;
typedef __attribute__((ext_vector_type(16))) float  f32x16;

typedef const void __attribute__((address_space(1))) * gptr_as1;
typedef void       __attribute__((address_space(3))) * lptr_as3;

static __device__ __forceinline__ void gload_lds16(const void* g, void* l){
  __builtin_amdgcn_global_load_lds((gptr_as1)g, (lptr_as3)l, 16, 0, 0);
}

static __device__ __forceinline__ unsigned short f2bf(float f){
  union { float f; unsigned u; } v; v.f = f;
  return (unsigned short)((v.u + 0x7FFFu + ((v.u >> 16) & 1u)) >> 16);
}

static __device__ __forceinline__ f32x4 mfma16(bf16x8 a, bf16x8 b, f32x4 c){
  return __builtin_amdgcn_mfma_f32_16x16x32_bf16(a, b, c, 0, 0, 0);
}
static __device__ __forceinline__ f32x16 mfma32(bf16x8 a, bf16x8 b, f32x16 c){
  return __builtin_amdgcn_mfma_f32_32x32x16_bf16(a, b, c, 0, 0, 0);
}
static __device__ __forceinline__ unsigned cvt_pk_bf16(float lo, float hi){
  unsigned r;
  asm("v_cvt_pk_bf16_f32 %0, %1, %2" : "=v"(r) : "v"(lo), "v"(hi));
  return r;
}

// fold softmax scale AND log2(e) into q: exp(s) == exp2(s')
#define QSCALE 0.18033688011112042f   // 0.125 * log2(e)

// ---------------- cast x (f32 -> bf16), vectorized ----------------
__global__ __launch_bounds__(256) void cast_x_kernel(const float* __restrict__ in,
                                                     unsigned short* __restrict__ out){
  int i = blockIdx.x * 256 + threadIdx.x;
  float4 v = *(const float4*)(in + (size_t)i * 4);
  ushort4 o;
  o.x = f2bf(v.x); o.y = f2bf(v.y); o.z = f2bf(v.z); o.w = f2bf(v.w);
  *(ushort4*)(out + (size_t)i * 4) = o;
}

// -------- transpose + cast: in [K][N] f32  ->  out [N][K] bf16 --------
__global__ __launch_bounds__(256) void transpose_cast_kernel(const float* __restrict__ in,
                                                             unsigned short* __restrict__ out,
                                                             int K, int N){
  __shared__ float tile[32][33];
  int n0 = blockIdx.x * 32, k0 = blockIdx.y * 32;
  int tx = threadIdx.x & 31, ty = threadIdx.x >> 5;
  #pragma unroll
  for (int r = ty; r < 32; r += 8)
    tile[r][tx] = in[(size_t)(k0 + r) * N + n0 + tx];
  __syncthreads();
  #pragma unroll
  for (int r = ty; r < 32; r += 8)
    out[(size_t)(n0 + r) * K + k0 + tx] = f2bf(tile[tx][r]);
}

// ---------------- bf16 MFMA GEMM (m97 structure) ----------------
template<int MODE>
__global__ __launch_bounds__(256) void gemm_bf16_kernel(
    const unsigned short* __restrict__ A,
    const unsigned short* __restrict__ Bt,
    const float* __restrict__ bias,
    float* __restrict__ outF,
    unsigned short* __restrict__ qo,
    unsigned short* __restrict__ ko,
    unsigned short* __restrict__ vTo,
    int Kdim, int Ndim)
{
  __shared__ unsigned short As[128 * 32];
  __shared__ unsigned short Bs[128 * 32];

  const int nwg  = gridDim.x * gridDim.y;
  const int orig = blockIdx.y * gridDim.x + blockIdx.x;
  const int swz  = (orig & 7) * (nwg >> 3) + (orig >> 3);
  const int n0 = (swz % gridDim.x) * 128;
  const int m0 = (swz / gridDim.x) * 128;

  const int tid = threadIdx.x, lane = tid & 63, w = tid >> 6;
  const int wm = w & 1, wn = w >> 1;
  const int lrow = lane & 15, kseg = lane >> 4;
  const int s16  = lane >> 2;
  const int sch  = lane & 3;

  f32x4 acc[4][4] = {};

  for (int kt = 0; kt < Kdim; kt += 32){
    #pragma unroll
    for (int j = 0; j < 2; ++j){
      const int idx = (w << 1) + j;
      const int row = (idx << 4) + s16;
      const int c4  = sch ^ (row & 3);
      gload_lds16(A  + (size_t)(m0 + row) * Kdim + kt + c4 * 8, &As[idx * 512]);
      gload_lds16(Bt + (size_t)(n0 + row) * Kdim + kt + c4 * 8, &Bs[idx * 512]);
    }
    __syncthreads();

    bf16x8 af[4], bfr[4];
    #pragma unroll
    for (int mi = 0; mi < 4; ++mi){
      const int row = wm * 64 + mi * 16 + lrow;
      af[mi] = *(const bf16x8*)&As[row * 32 + ((kseg ^ (row & 3)) << 3)];
    }
    #pragma unroll
    for (int ni = 0; ni < 4; ++ni){
      const int row = wn * 64 + ni * 16 + lrow;
      bfr[ni] = *(const bf16x8*)&Bs[row * 32 + ((kseg ^ (row & 3)) << 3)];
    }
    #pragma unroll
    for (int mi = 0; mi < 4; ++mi)
      #pragma unroll
      for (int ni = 0; ni < 4; ++ni)
        acc[mi][ni] = mfma16(af[mi], bfr[ni], acc[mi][ni]);
    __syncthreads();
  }

  #pragma unroll
  for (int ni = 0; ni < 4; ++ni){
    const int gc = n0 + wn * 64 + ni * 16 + lrow;
    const float bv = bias[gc];
    #pragma unroll
    for (int mi = 0; mi < 4; ++mi){
      #pragma unroll
      for (int r_ = 0; r_ < 4; ++r_){
        const int gr = m0 + wm * 64 + mi * 16 + (kseg << 2) + r_;
        float val = acc[mi][ni][r_] + bv;
        if (MODE == 1){
          outF[(size_t)gr * Ndim + gc] = val;
        } else {
          const int bb = gr >> 11, t = gr & (TSEQ - 1);
          if (gc < DMODEL){
            const int h = gc >> 6, d = gc & 63;
            qo[(((size_t)bb * NHEAD + h) * TSEQ + t) * 64 + d] = f2bf(val * QSCALE);
          } else if (gc < 2 * DMODEL){
            const int c = gc - DMODEL, h = c >> 6, d = c & 63;
            ko[(((size_t)bb * NHEAD + h) * TSEQ + t) * 64 + d] = f2bf(val);
          } else {
            const int c = gc - 2 * DMODEL, h = c >> 6, d = c & 63;
            vTo[(((size_t)bb * NHEAD + h) * 64 + d) * TSEQ + t] = f2bf(val);
          }
        }
      }
    }
  }
}

// ---------------- causal flash attention, 32x32 swapped-QK^T structure ----------------
// Block = 4 waves x 32 q-rows = 128-row q-tile; pairs {p, 15-p} -> uniform 36 KV-iters.
// S^T = mfma(K, Q): lane owns P-row (q = lane&31) -> lane-local softmax.
// P -> bf16 in-register (cvt_pk + permlane32_swap) -> PV B-operand. O = mfma(V^T, P): col=q.
__global__ __launch_bounds__(256, 2) void attn_kernel(
    const unsigned short* __restrict__ qg,   // [BH][T][64], pre-scaled by 0.125*log2e
    const unsigned short* __restrict__ kg,   // [BH][T][64]
    const unsigned short* __restrict__ vTg,  // [BH][64][T]
    unsigned short* __restrict__ y)          // [B*T][1024] bf16
{
  __shared__ unsigned short Ks[2][64 * 64];  // [key][d], chunk c holds src chunk c^(key&7)
  __shared__ unsigned short Vs[2][64 * 64];  // [d][key], chunk c holds src chunk c^(d&7)

  const int nwg  = gridDim.x * gridDim.y;    // 512
  const int orig = blockIdx.y * gridDim.x + blockIdx.x;
  const int swz  = (orig & 7) * (nwg >> 3) + (orig >> 3);
  const int p  = swz & 7;                    // pair 0..7
  const int bh = swz >> 3;                   // 0..63, 8 consecutive bh per XCD
  const int bb = bh >> 4, h = bh & (NHEAD - 1);

  const int tid = threadIdx.x, lane = tid & 63, w = tid >> 6;
  const int l31 = lane & 31, hi = lane >> 5;
  const int sr8 = lane >> 3, sc8 = lane & 7;  // staging geometry

  auto stage = [&](int buf, int kb){
    const int kt0 = kb * 64;
    #pragma unroll
    for (int j = 0; j < 2; ++j){
      const int idx = (w << 1) + j;          // 0..7
      const int r   = (idx << 3) + sr8;      // 0..63
      const int c8  = sc8 ^ (r & 7);
      gload_lds16(kg  + ((size_t)bh * TSEQ + kt0 + r) * 64 + c8 * 8, &Ks[buf][idx * 512]);
      gload_lds16(vTg + ((size_t)bh * 64 + r) * TSEQ + kt0 + c8 * 8, &Vs[buf][idx * 512]);
    }
  };

  int cur = 0;
  for (int hf = 0; hf < 2; ++hf){
    const int qt  = hf ? (15 - p) : p;
    const int q0w = qt * 128 + w * 32;
    const int q   = q0w + l31;
    const int nkv = 2 * qt + 2;

    // Q fragments (B-operand rows = q): qf[dk] = Q[q][16dk + 8hi .. +7]
    bf16x8 qf[4];
    {
      const unsigned short* qp = qg + ((size_t)bh * TSEQ + q) * 64 + hi * 8;
      #pragma unroll
      for (int dk = 0; dk < 4; ++dk) qf[dk] = *(const bf16x8*)(qp + dk * 16);
    }

    f32x16 o0 = {}, o1 = {};
    float m_run = -1e30f, l_run = 0.f;

    stage(cur, 0);
    __syncthreads();

    for (int kb = 0; kb < nkv; ++kb){
      const int kt0 = kb * 64;
      if (kb + 1 < nkv) stage(cur ^ 1, kb + 1);   // prefetch next tile (hidden under compute)

      if (kt0 <= q0w + 31){                        // wave-uniform: skip fully-masked tiles
        // ---- S^T = K Q^T : two 32-key blocks ----
        f32x16 s0 = {}, s1 = {};
        #pragma unroll
        for (int dk = 0; dk < 4; ++dk){
          const int c = ((dk << 1) + hi) ^ (l31 & 7);
          bf16x8 k0 = *(const bf16x8*)&Ks[cur][ l31       * 64 + c * 8];
          bf16x8 k1 = *(const bf16x8*)&Ks[cur][(l31 + 32) * 64 + c * 8];
          s0 = mfma32(k0, qf[dk], s0);
          s1 = mfma32(k1, qf[dk], s1);
        }
        // ---- causal mask (diagonal region only) ----
        if (kt0 + 63 > q0w){
          #pragma unroll
          for (int r = 0; r < 16; ++r){
            const int key = kt0 + (r & 3) + 8 * (r >> 2) + 4 * hi;
            if (key      > q) s0[r] = -1e30f;
            if (key + 32 > q) s1[r] = -1e30f;
          }
        }
        // ---- lane-local softmax (tree max over 32 + one cross-half shuffle) ----
        float t16[16];
        #pragma unroll
        for (int i = 0; i < 16; ++i) t16[i] = fmaxf(s0[i], s1[i]);
        #pragma unroll
        for (int st = 8; st >= 1; st >>= 1)
          #pragma unroll
          for (int i = 0; i < 16; ++i) if (i < st) t16[i] = fmaxf(t16[i], t16[i + st]);
        float mx = fmaxf(t16[0], __shfl_xor(t16[0], 32));
        const float mnew = fmaxf(m_run, mx);
        const float resc = __builtin_amdgcn_exp2f(m_run - mnew);
        m_run = mnew;
        float sa = 0.f, sb = 0.f, sc_ = 0.f, sd = 0.f;
        #pragma unroll
        for (int i = 0; i < 4; ++i){
          s0[i]      = __builtin_amdgcn_exp2f(s0[i]      - mnew); sa += s0[i];
          s0[i + 4]  = __builtin_amdgcn_exp2f(s0[i + 4]  - mnew); sb += s0[i + 4];
          s0[i + 8]  = __builtin_amdgcn_exp2f(s0[i + 8]  - mnew); sc_ += s0[i + 8];
          s0[i + 12] = __builtin_amdgcn_exp2f(s0[i + 12] - mnew); sd += s0[i + 12];
          s1[i]      = __builtin_amdgcn_exp2f(s1[i]      - mnew); sa += s1[i];
          s1[i + 4]  = __builtin_amdgcn_exp2f(s1[i + 4]  - mnew); sb += s1[i + 4];
          s1[i + 8]  = __builtin_amdgcn_exp2f(s1[i + 8]  - mnew); sc_ += s1[i + 8];
          s1[i + 12] = __builtin_amdgcn_exp2f(s1[i + 12] - mnew); sd += s1[i + 12];
        }
        float sum = (sa + sb) + (sc_ + sd);
        sum += __shfl_xor(sum, 32);
        l_run = l_run * resc + sum;
        #pragma unroll
        for (int r = 0; r < 16; ++r){ o0[r] *= resc; o1[r] *= resc; }
        // ---- pack P -> bf16 fragments (cvt_pk + permlane32_swap) ----
        bf16x8 pf[4];
        #pragma unroll
        for (int kc = 0; kc < 4; ++kc){
          const int base = (kc & 1) * 8;
          float p0,p1,p2,p3,p4,p5,p6,p7;
          if (kc < 2){ p0=s0[base];p1=s0[base+1];p2=s0[base+2];p3=s0[base+3];
                       p4=s0[base+4];p5=s0[base+5];p6=s0[base+6];p7=s0[base+7]; }
          else       { p0=s1[base];p1=s1[base+1];p2=s1[base+2];p3=s1[base+3];
                       p4=s1[base+4];p5=s1[base+5];p6=s1[base+6];p7=s1[base+7]; }
          unsigned X0 = cvt_pk_bf16(p0, p1), X1 = cvt_pk_bf16(p2, p3);
          unsigned Y0 = cvt_pk_bf16(p4, p5), Y1 = cvt_pk_bf16(p6, p7);
          auto sA = __builtin_amdgcn_permlane32_swap(X0, Y0, false, false);
          auto sB = __builtin_amdgcn_permlane32_swap(X1, Y1, false, false);
          union { unsigned u[4]; bf16x8 v; } fr;
          fr.u[0] = sA[0]; fr.u[1] = sB[0]; fr.u[2] = sA[1]; fr.u[3] = sB[1];
          pf[kc] = fr.v;
        }
        // ---- O += V^T P : A = V^T rows d, B = P rows q ----
        #pragma unroll
        for (int kc = 0; kc < 4; ++kc){
          const int c0 = ((kc << 1) + hi) ^ (l31 & 7);
          bf16x8 v0 = *(const bf16x8*)&Vs[cur][ l31       * 64 + c0 * 8];
          bf16x8 v1 = *(const bf16x8*)&Vs[cur][(l31 + 32) * 64 + c0 * 8];
          o0 = mfma32(v0, pf[kc], o0);
          o1 = mfma32(v1, pf[kc], o1);
        }
      }
      __syncthreads();   // drains prefetch vmcnt + guards dbuf reuse
      cur ^= 1;
    }

    // ---- epilogue: y[t][h*64+d] = O[d][q]/l ----
    const float rl = 1.0f / l_run;
    unsigned short* yrow = y + ((size_t)bb * TSEQ + q) * DMODEL + h * 64;
    #pragma unroll
    for (int i = 0; i < 8; ++i){
      const int r = 2 * i;
      const int d = (r & 3) + 8 * (r >> 2) + 4 * hi;
      unsigned pk0 = (unsigned)f2bf(o0[r] * rl) | ((unsigned)f2bf(o0[r + 1] * rl) << 16);
      unsigned pk1 = (unsigned)f2bf(o1[r] * rl) | ((unsigned)f2bf(o1[r + 1] * rl) << 16);
      *(unsigned*)(yrow + d)      = pk0;
      *(unsigned*)(yrow + d + 32) = pk1;
    }
  }
}

extern "C" void kernel_launch(void* const* d_in, const int* in_sizes, int n_in,
                              void* d_out, int out_size, void* d_ws, size_t ws_size,
                              hipStream_t stream) {
  const float* x    = (const float*)d_in[0];
  const float* Wqkv = (const float*)d_in[1];
  const float* bqkv = (const float*)d_in[2];
  const float* Wo   = (const float*)d_in[3];
  const float* bo   = (const float*)d_in[4];
  float* out = (float*)d_out;

  char* ws = (char*)d_ws;
  unsigned short* x_bf   = (unsigned short*)(ws);
  unsigned short* Wqkv_t = (unsigned short*)(ws + (16u << 20));
  unsigned short* Wo_t   = (unsigned short*)(ws + (22u << 20));
  unsigned short* q_ws   = (unsigned short*)(ws + (24u << 20));
  unsigned short* k_ws   = (unsigned short*)(ws + (40u << 20));
  unsigned short* vT_ws  = (unsigned short*)(ws + (56u << 20));
  unsigned short* y_bf   = x_bf;   // x_bf dead after GEMM1

  cast_x_kernel<<<8192, 256, 0, stream>>>(x, x_bf);
  transpose_cast_kernel<<<dim3(96, 32), 256, 0, stream>>>(Wqkv, Wqkv_t, 1024, 3072);
  transpose_cast_kernel<<<dim3(32, 32), 256, 0, stream>>>(Wo, Wo_t, 1024, 1024);

  gemm_bf16_kernel<0><<<dim3(24, 64), 256, 0, stream>>>(x_bf, Wqkv_t, bqkv,
                                                        nullptr, q_ws, k_ws, vT_ws, 1024, 3072);
  attn_kernel<<<dim3(8, 64), 256, 0, stream>>>(q_ws, k_ws, vT_ws, y_bf);
  gemm_bf16_kernel<1><<<dim3(8, 64), 256, 0, stream>>>(y_bf, Wo_t, bo,
                                                       out, nullptr, nullptr, nullptr, 1024, 1024);
}

// Round 4
// 187.395 us; speedup vs baseline: 3.3703x; 1.0772x over previous
//
#include <hip/hip_runtime.h>
#include <hip/hip_bf16.h>

// Problem constants
#define TSEQ   2048
#define NHEAD  16
#define DMODEL 1024

typedef __attribute__((ext_vector_type(8)))  __bf16 bf16x8;
typedef __attribute__((ext_vector_type(4)))  float  f32x4;
typedef __attribute__((ext_vector_type(16))) float  f32x16;

typedef const void __attribute__((address_space(1))) * gptr_as1;
typedef void       __attribute__((address_space(3))) * lptr_as3;

static __device__ __forceinline__ void gload_lds16(const void* g, void* l){
  __builtin_amdgcn_global_load_lds((gptr_as1)g, (lptr_as3)l, 16, 0, 0);
}

static __device__ __forceinline__ unsigned short f2bf(float f){
  union { float f; unsigned u; } v; v.f = f;
  return (unsigned short)((v.u + 0x7FFFu + ((v.u >> 16) & 1u)) >> 16);
}

static __device__ __forceinline__ f32x4 mfma16(bf16x8 a, bf16x8 b, f32x4 c){
  return __builtin_amdgcn_mfma_f32_16x16x32_bf16(a, b, c, 0, 0, 0);
}
static __device__ __forceinline__ f32x16 mfma32(bf16x8 a, bf16x8 b, f32x16 c){
  return __builtin_amdgcn_mfma_f32_32x32x16_bf16(a, b, c, 0, 0, 0);
}
static __device__ __forceinline__ unsigned cvt_pk_bf16(float lo, float hi){
  unsigned r;
  asm("v_cvt_pk_bf16_f32 %0, %1, %2" : "=v"(r) : "v"(lo), "v"(hi));
  return r;
}

// fold softmax scale AND log2(e) into q: exp(s) == exp2(s')
#define QSCALE 0.18033688011112042f   // 0.125 * log2(e)

// ---------------- cast x (f32 -> bf16), vectorized ----------------
__global__ __launch_bounds__(256) void cast_x_kernel(const float* __restrict__ in,
                                                     unsigned short* __restrict__ out){
  int i = blockIdx.x * 256 + threadIdx.x;
  float4 v = *(const float4*)(in + (size_t)i * 4);
  ushort4 o;
  o.x = f2bf(v.x); o.y = f2bf(v.y); o.z = f2bf(v.z); o.w = f2bf(v.w);
  *(ushort4*)(out + (size_t)i * 4) = o;
}

// -------- transpose + cast: in [K][N] f32  ->  out [N][K] bf16 --------
__global__ __launch_bounds__(256) void transpose_cast_kernel(const float* __restrict__ in,
                                                             unsigned short* __restrict__ out,
                                                             int K, int N){
  __shared__ float tile[32][33];
  int n0 = blockIdx.x * 32, k0 = blockIdx.y * 32;
  int tx = threadIdx.x & 31, ty = threadIdx.x >> 5;
  #pragma unroll
  for (int r = ty; r < 32; r += 8)
    tile[r][tx] = in[(size_t)(k0 + r) * N + n0 + tx];
  __syncthreads();
  #pragma unroll
  for (int r = ty; r < 32; r += 8)
    out[(size_t)(n0 + r) * K + k0 + tx] = f2bf(tile[tx][r]);
}

// -------- v transpose: [BH][T][64] -> [BH][64][T], LDS-free --------
__global__ __launch_bounds__(256) void transpose_v_kernel(
    const unsigned short* __restrict__ vin,
    unsigned short* __restrict__ vT){
  const int bh = blockIdx.y;
  const int t0 = blockIdx.x * 32 + (threadIdx.x >> 6) * 8;
  const int d  = threadIdx.x & 63;
  const unsigned short* src = vin + ((size_t)bh * TSEQ + t0) * 64 + d;
  ushort4 a, b;
  a.x = src[0];   a.y = src[64];  a.z = src[128]; a.w = src[192];
  b.x = src[256]; b.y = src[320]; b.z = src[384]; b.w = src[448];
  unsigned short* dst = vT + ((size_t)bh * 64 + d) * TSEQ + t0;
  *(ushort4*)dst       = a;
  *(ushort4*)(dst + 4) = b;
}

// ---------------- bf16 MFMA GEMM (m97 structure + 2-phase dbuf) ----------------
// MODE 0: qkv -> q,k,v all [BH][T][64] coalesced (v transposed separately)
// MODE 1: out projection -> fp32 out [M][N]
// MODE 2: qkv -> q,k [BH][T][64], v scattered direct to vT (ws-size fallback)
template<int MODE>
__global__ __launch_bounds__(256) void gemm_bf16_kernel(
    const unsigned short* __restrict__ A,
    const unsigned short* __restrict__ Bt,
    const float* __restrict__ bias,
    float* __restrict__ outF,
    unsigned short* __restrict__ qo,
    unsigned short* __restrict__ ko,
    unsigned short* __restrict__ vo,
    int Kdim, int Ndim)
{
  __shared__ unsigned short As[2][128 * 32];
  __shared__ unsigned short Bs[2][128 * 32];

  const int nwg  = gridDim.x * gridDim.y;
  const int orig = blockIdx.y * gridDim.x + blockIdx.x;
  const int swz  = (orig & 7) * (nwg >> 3) + (orig >> 3);
  const int n0 = (swz % gridDim.x) * 128;
  const int m0 = (swz / gridDim.x) * 128;

  const int tid = threadIdx.x, lane = tid & 63, w = tid >> 6;
  const int wm = w & 1, wn = w >> 1;
  const int lrow = lane & 15, kseg = lane >> 4;
  const int s16  = lane >> 2;                    // staging row within 16-row slab
  const int sc4  = (lane & 3) ^ ((s16 >> 1) & 3); // pre-swizzled source chunk

  auto stage = [&](int buf, int ktE){
    #pragma unroll
    for (int j = 0; j < 2; ++j){
      const int idx = (w << 1) + j;              // 0..7
      const int row = (idx << 4) + s16;          // 0..127
      gload_lds16(A  + (size_t)(m0 + row) * Kdim + ktE + sc4 * 8, &As[buf][idx * 512]);
      gload_lds16(Bt + (size_t)(n0 + row) * Kdim + ktE + sc4 * 8, &Bs[buf][idx * 512]);
    }
  };

  f32x4 acc[4][4] = {};
  const int nkt = Kdim >> 5;
  stage(0, 0);
  __syncthreads();
  int cur = 0;

  for (int t = 0; t < nkt; ++t){
    if (t + 1 < nkt) stage(cur ^ 1, (t + 1) << 5);   // prefetch under compute

    const int ksw = (kseg ^ ((lrow >> 1) & 3)) << 3; // conflict-free slot swizzle
    bf16x8 af[4], bfr[4];
    #pragma unroll
    for (int mi = 0; mi < 4; ++mi)
      af[mi] = *(const bf16x8*)&As[cur][(wm * 64 + mi * 16 + lrow) * 32 + ksw];
    #pragma unroll
    for (int ni = 0; ni < 4; ++ni)
      bfr[ni] = *(const bf16x8*)&Bs[cur][(wn * 64 + ni * 16 + lrow) * 32 + ksw];
    #pragma unroll
    for (int mi = 0; mi < 4; ++mi)
      #pragma unroll
      for (int ni = 0; ni < 4; ++ni)
        acc[mi][ni] = mfma16(af[mi], bfr[ni], acc[mi][ni]);

    __syncthreads();   // drains prefetch vmcnt; guards dbuf reuse
    cur ^= 1;
  }

  // epilogue: C/D layout col=lane&15, row=(lane>>4)*4+reg
  #pragma unroll
  for (int ni = 0; ni < 4; ++ni){
    const int gc = n0 + wn * 64 + ni * 16 + lrow;
    const float bv = bias[gc];
    #pragma unroll
    for (int mi = 0; mi < 4; ++mi){
      #pragma unroll
      for (int r_ = 0; r_ < 4; ++r_){
        const int gr = m0 + wm * 64 + mi * 16 + (kseg << 2) + r_;
        float val = acc[mi][ni][r_] + bv;
        if (MODE == 1){
          outF[(size_t)gr * Ndim + gc] = val;
        } else {
          const int bb = gr >> 11, tt = gr & (TSEQ - 1);
          const int c = gc & (DMODEL - 1), hh = c >> 6, d = c & 63;
          const size_t off = (((size_t)bb * NHEAD + hh) * TSEQ + tt) * 64 + d;
          if (gc < DMODEL)            qo[off] = f2bf(val * QSCALE);
          else if (gc < 2 * DMODEL)   ko[off] = f2bf(val);
          else if (MODE == 0)         vo[off] = f2bf(val);
          else  vo[(((size_t)bb * NHEAD + hh) * 64 + d) * TSEQ + tt] = f2bf(val);
        }
      }
    }
  }
}

// ---------------- causal flash attention, 32x32 swapped-QK^T structure ----------------
__global__ __launch_bounds__(256, 2) void attn_kernel(
    const unsigned short* __restrict__ qg,   // [BH][T][64], pre-scaled by 0.125*log2e
    const unsigned short* __restrict__ kg,   // [BH][T][64]
    const unsigned short* __restrict__ vTg,  // [BH][64][T]
    unsigned short* __restrict__ y)          // [B*T][1024] bf16
{
  __shared__ unsigned short Ks[2][64 * 64];
  __shared__ unsigned short Vs[2][64 * 64];

  const int nwg  = gridDim.x * gridDim.y;    // 512
  const int orig = blockIdx.y * gridDim.x + blockIdx.x;
  const int swz  = (orig & 7) * (nwg >> 3) + (orig >> 3);
  const int p  = swz & 7;
  const int bh = swz >> 3;
  const int bb = bh >> 4, h = bh & (NHEAD - 1);

  const int tid = threadIdx.x, lane = tid & 63, w = tid >> 6;
  const int l31 = lane & 31, hi = lane >> 5;
  const int sr8 = lane >> 3, sc8 = lane & 7;

  auto stage = [&](int buf, int kb){
    const int kt0 = kb * 64;
    #pragma unroll
    for (int j = 0; j < 2; ++j){
      const int idx = (w << 1) + j;
      const int r   = (idx << 3) + sr8;
      const int c8  = sc8 ^ (r & 7);
      gload_lds16(kg  + ((size_t)bh * TSEQ + kt0 + r) * 64 + c8 * 8, &Ks[buf][idx * 512]);
      gload_lds16(vTg + ((size_t)bh * 64 + r) * TSEQ + kt0 + c8 * 8, &Vs[buf][idx * 512]);
    }
  };

  int cur = 0;
  for (int hf = 0; hf < 2; ++hf){
    const int qt  = hf ? (15 - p) : p;
    const int q0w = qt * 128 + w * 32;
    const int q   = q0w + l31;
    const int nkv = 2 * qt + 2;

    bf16x8 qf[4];
    {
      const unsigned short* qp = qg + ((size_t)bh * TSEQ + q) * 64 + hi * 8;
      #pragma unroll
      for (int dk = 0; dk < 4; ++dk) qf[dk] = *(const bf16x8*)(qp + dk * 16);
    }

    f32x16 o0 = {}, o1 = {};
    float m_run = -1e30f, l_run = 0.f;

    stage(cur, 0);
    __syncthreads();

    for (int kb = 0; kb < nkv; ++kb){
      const int kt0 = kb * 64;
      if (kb + 1 < nkv) stage(cur ^ 1, kb + 1);

      if (kt0 <= q0w + 31){
        f32x16 s0 = {}, s1 = {};
        #pragma unroll
        for (int dk = 0; dk < 4; ++dk){
          const int c = ((dk << 1) + hi) ^ (l31 & 7);
          bf16x8 k0 = *(const bf16x8*)&Ks[cur][ l31       * 64 + c * 8];
          bf16x8 k1 = *(const bf16x8*)&Ks[cur][(l31 + 32) * 64 + c * 8];
          s0 = mfma32(k0, qf[dk], s0);
          s1 = mfma32(k1, qf[dk], s1);
        }
        if (kt0 + 63 > q0w){
          #pragma unroll
          for (int r = 0; r < 16; ++r){
            const int key = kt0 + (r & 3) + 8 * (r >> 2) + 4 * hi;
            if (key      > q) s0[r] = -1e30f;
            if (key + 32 > q) s1[r] = -1e30f;
          }
        }
        float t16[16];
        #pragma unroll
        for (int i = 0; i < 16; ++i) t16[i] = fmaxf(s0[i], s1[i]);
        #pragma unroll
        for (int st = 8; st >= 1; st >>= 1)
          #pragma unroll
          for (int i = 0; i < 16; ++i) if (i < st) t16[i] = fmaxf(t16[i], t16[i + st]);
        float mx = fmaxf(t16[0], __shfl_xor(t16[0], 32));
        const float mnew = fmaxf(m_run, mx);
        const float resc = __builtin_amdgcn_exp2f(m_run - mnew);
        m_run = mnew;
        float sa = 0.f, sb = 0.f, sc_ = 0.f, sd = 0.f;
        #pragma unroll
        for (int i = 0; i < 4; ++i){
          s0[i]      = __builtin_amdgcn_exp2f(s0[i]      - mnew); sa += s0[i];
          s0[i + 4]  = __builtin_amdgcn_exp2f(s0[i + 4]  - mnew); sb += s0[i + 4];
          s0[i + 8]  = __builtin_amdgcn_exp2f(s0[i + 8]  - mnew); sc_ += s0[i + 8];
          s0[i + 12] = __builtin_amdgcn_exp2f(s0[i + 12] - mnew); sd += s0[i + 12];
          s1[i]      = __builtin_amdgcn_exp2f(s1[i]      - mnew); sa += s1[i];
          s1[i + 4]  = __builtin_amdgcn_exp2f(s1[i + 4]  - mnew); sb += s1[i + 4];
          s1[i + 8]  = __builtin_amdgcn_exp2f(s1[i + 8]  - mnew); sc_ += s1[i + 8];
          s1[i + 12] = __builtin_amdgcn_exp2f(s1[i + 12] - mnew); sd += s1[i + 12];
        }
        float sum = (sa + sb) + (sc_ + sd);
        sum += __shfl_xor(sum, 32);
        l_run = l_run * resc + sum;
        #pragma unroll
        for (int r = 0; r < 16; ++r){ o0[r] *= resc; o1[r] *= resc; }

        bf16x8 pf[4];
        #pragma unroll
        for (int kc = 0; kc < 4; ++kc){
          const int base = (kc & 1) * 8;
          float p0,p1,p2,p3,p4,p5,p6,p7;
          if (kc < 2){ p0=s0[base];p1=s0[base+1];p2=s0[base+2];p3=s0[base+3];
                       p4=s0[base+4];p5=s0[base+5];p6=s0[base+6];p7=s0[base+7]; }
          else       { p0=s1[base];p1=s1[base+1];p2=s1[base+2];p3=s1[base+3];
                       p4=s1[base+4];p5=s1[base+5];p6=s1[base+6];p7=s1[base+7]; }
          unsigned X0 = cvt_pk_bf16(p0, p1), X1 = cvt_pk_bf16(p2, p3);
          unsigned Y0 = cvt_pk_bf16(p4, p5), Y1 = cvt_pk_bf16(p6, p7);
          auto sA = __builtin_amdgcn_permlane32_swap(X0, Y0, false, false);
          auto sB = __builtin_amdgcn_permlane32_swap(X1, Y1, false, false);
          union { unsigned u[4]; bf16x8 v; } fr;
          fr.u[0] = sA[0]; fr.u[1] = sB[0]; fr.u[2] = sA[1]; fr.u[3] = sB[1];
          pf[kc] = fr.v;
        }
        #pragma unroll
        for (int kc = 0; kc < 4; ++kc){
          const int c0 = ((kc << 1) + hi) ^ (l31 & 7);
          bf16x8 v0 = *(const bf16x8*)&Vs[cur][ l31       * 64 + c0 * 8];
          bf16x8 v1 = *(const bf16x8*)&Vs[cur][(l31 + 32) * 64 + c0 * 8];
          o0 = mfma32(v0, pf[kc], o0);
          o1 = mfma32(v1, pf[kc], o1);
        }
      }
      __syncthreads();
      cur ^= 1;
    }

    const float rl = 1.0f / l_run;
    unsigned short* yrow = y + ((size_t)bb * TSEQ + q) * DMODEL + h * 64;
    #pragma unroll
    for (int i = 0; i < 8; ++i){
      const int r = 2 * i;
      const int d = (r & 3) + 8 * (r >> 2) + 4 * hi;
      unsigned pk0 = (unsigned)f2bf(o0[r] * rl) | ((unsigned)f2bf(o0[r + 1] * rl) << 16);
      unsigned pk1 = (unsigned)f2bf(o1[r] * rl) | ((unsigned)f2bf(o1[r + 1] * rl) << 16);
      *(unsigned*)(yrow + d)      = pk0;
      *(unsigned*)(yrow + d + 32) = pk1;
    }
  }
}

extern "C" void kernel_launch(void* const* d_in, const int* in_sizes, int n_in,
                              void* d_out, int out_size, void* d_ws, size_t ws_size,
                              hipStream_t stream) {
  const float* x    = (const float*)d_in[0];
  const float* Wqkv = (const float*)d_in[1];
  const float* bqkv = (const float*)d_in[2];
  const float* Wo   = (const float*)d_in[3];
  const float* bo   = (const float*)d_in[4];
  float* out = (float*)d_out;

  char* ws = (char*)d_ws;
  unsigned short* x_bf   = (unsigned short*)(ws);
  unsigned short* Wqkv_t = (unsigned short*)(ws + (16u << 20));
  unsigned short* Wo_t   = (unsigned short*)(ws + (22u << 20));
  unsigned short* q_ws   = (unsigned short*)(ws + (24u << 20));
  unsigned short* k_ws   = (unsigned short*)(ws + (40u << 20));
  unsigned short* v_ws   = (unsigned short*)(ws + (56u << 20));
  unsigned short* vT_ws  = (unsigned short*)(ws + (72u << 20));
  unsigned short* y_bf   = x_bf;   // x_bf dead after GEMM1

  cast_x_kernel<<<8192, 256, 0, stream>>>(x, x_bf);
  transpose_cast_kernel<<<dim3(96, 32), 256, 0, stream>>>(Wqkv, Wqkv_t, 1024, 3072);
  transpose_cast_kernel<<<dim3(32, 32), 256, 0, stream>>>(Wo, Wo_t, 1024, 1024);

  if (ws_size >= ((size_t)88 << 20)) {
    // coalesced v writes + dedicated transpose
    gemm_bf16_kernel<0><<<dim3(24, 64), 256, 0, stream>>>(x_bf, Wqkv_t, bqkv,
                                                          nullptr, q_ws, k_ws, v_ws, 1024, 3072);
    transpose_v_kernel<<<dim3(64, 64), 256, 0, stream>>>(v_ws, vT_ws);
  } else {
    // fallback: scatter vT directly from GEMM1, reuse v_ws slot as vT
    vT_ws = v_ws;
    gemm_bf16_kernel<2><<<dim3(24, 64), 256, 0, stream>>>(x_bf, Wqkv_t, bqkv,
                                                          nullptr, q_ws, k_ws, vT_ws, 1024, 3072);
  }
  attn_kernel<<<dim3(8, 64), 256, 0, stream>>>(q_ws, k_ws, vT_ws, y_bf);
  gemm_bf16_kernel<1><<<dim3(8, 64), 256, 0, stream>>>(y_bf, Wo_t, bo,
                                                       out, nullptr, nullptr, nullptr, 1024, 1024);
}

// Round 5
// 186.453 us; speedup vs baseline: 3.3874x; 1.0051x over previous
//
#include <hip/hip_runtime.h>
#include <hip/hip_bf16.h>

// Problem constants
#define TSEQ   2048
#define NHEAD  16
#define DMODEL 1024

typedef __attribute__((ext_vector_type(8)))  __bf16 bf16x8;
typedef __attribute__((ext_vector_type(4)))  float  f32x4;
typedef __attribute__((ext_vector_type(16))) float  f32x16;

typedef const void __attribute__((address_space(1))) * gptr_as1;
typedef void       __attribute__((address_space(3))) * lptr_as3;

static __device__ __forceinline__ void gload_lds16(const void* g, void* l){
  __builtin_amdgcn_global_load_lds((gptr_as1)g, (lptr_as3)l, 16, 0, 0);
}

static __device__ __forceinline__ unsigned short f2bf(float f){
  union { float f; unsigned u; } v; v.f = f;
  return (unsigned short)((v.u + 0x7FFFu + ((v.u >> 16) & 1u)) >> 16);
}

static __device__ __forceinline__ f32x4 mfma16(bf16x8 a, bf16x8 b, f32x4 c){
  return __builtin_amdgcn_mfma_f32_16x16x32_bf16(a, b, c, 0, 0, 0);
}
static __device__ __forceinline__ f32x16 mfma32(bf16x8 a, bf16x8 b, f32x16 c){
  return __builtin_amdgcn_mfma_f32_32x32x16_bf16(a, b, c, 0, 0, 0);
}
static __device__ __forceinline__ unsigned cvt_pk_bf16(float lo, float hi){
  unsigned r;
  asm("v_cvt_pk_bf16_f32 %0, %1, %2" : "=v"(r) : "v"(lo), "v"(hi));
  return r;
}

// fold softmax scale AND log2(e) into q: exp(s) == exp2(s')
#define QSCALE 0.18033688011112042f   // 0.125 * log2(e)

// ---------------- cast x (f32 -> bf16), vectorized ----------------
__global__ __launch_bounds__(256) void cast_x_kernel(const float* __restrict__ in,
                                                     unsigned short* __restrict__ out){
  int i = blockIdx.x * 256 + threadIdx.x;
  float4 v = *(const float4*)(in + (size_t)i * 4);
  ushort4 o;
  o.x = f2bf(v.x); o.y = f2bf(v.y); o.z = f2bf(v.z); o.w = f2bf(v.w);
  *(ushort4*)(out + (size_t)i * 4) = o;
}

// -------- transpose + cast: in [K][N] f32  ->  out [N][K] bf16 --------
__global__ __launch_bounds__(256) void transpose_cast_kernel(const float* __restrict__ in,
                                                             unsigned short* __restrict__ out,
                                                             int K, int N){
  __shared__ float tile[32][33];
  int n0 = blockIdx.x * 32, k0 = blockIdx.y * 32;
  int tx = threadIdx.x & 31, ty = threadIdx.x >> 5;
  #pragma unroll
  for (int r = ty; r < 32; r += 8)
    tile[r][tx] = in[(size_t)(k0 + r) * N + n0 + tx];
  __syncthreads();
  #pragma unroll
  for (int r = ty; r < 32; r += 8)
    out[(size_t)(n0 + r) * K + k0 + tx] = f2bf(tile[tx][r]);
}

// -------- v transpose: [BH][T][64] -> [BH][64][T], LDS-free --------
__global__ __launch_bounds__(256) void transpose_v_kernel(
    const unsigned short* __restrict__ vin,
    unsigned short* __restrict__ vT){
  const int bh = blockIdx.y;
  const int t0 = blockIdx.x * 32 + (threadIdx.x >> 6) * 8;
  const int d  = threadIdx.x & 63;
  const unsigned short* src = vin + ((size_t)bh * TSEQ + t0) * 64 + d;
  ushort4 a, b;
  a.x = src[0];   a.y = src[64];  a.z = src[128]; a.w = src[192];
  b.x = src[256]; b.y = src[320]; b.z = src[384]; b.w = src[448];
  unsigned short* dst = vT + ((size_t)bh * 64 + d) * TSEQ + t0;
  *(ushort4*)dst       = a;
  *(ushort4*)(dst + 4) = b;
}

// ---------------- bf16 MFMA GEMM (m97 structure, single-buffer, 6 blocks/CU) ----------
// MODE 0: qkv -> q,k,v all [BH][T][64], LDS-transposed coalesced epilogue
// MODE 1: out projection -> fp32 out [M][N], direct stores
// MODE 2: qkv fallback -> q,k [BH][T][64], v scattered direct to vT
template<int MODE>
__global__ __launch_bounds__(256) void gemm_bf16_kernel(
    const unsigned short* __restrict__ A,
    const unsigned short* __restrict__ Bt,
    const float* __restrict__ bias,
    float* __restrict__ outF,
    unsigned short* __restrict__ qo,
    unsigned short* __restrict__ ko,
    unsigned short* __restrict__ vo,
    int Kdim, int Ndim)
{
  __shared__ unsigned short As[128 * 32];   // 8 KB, single buffer
  __shared__ unsigned short Bs[128 * 32];

  const int nwg  = gridDim.x * gridDim.y;
  const int orig = blockIdx.y * gridDim.x + blockIdx.x;
  const int swz  = (orig & 7) * (nwg >> 3) + (orig >> 3);
  const int n0 = (swz % gridDim.x) * 128;
  const int m0 = (swz / gridDim.x) * 128;

  const int tid = threadIdx.x, lane = tid & 63, w = tid >> 6;
  const int wm = w & 1, wn = w >> 1;
  const int lrow = lane & 15, kseg = lane >> 4;
  const int s16  = lane >> 2;                     // staging row within 16-row slab
  const int sc4  = (lane & 3) ^ ((s16 >> 1) & 3); // pre-swizzled source chunk

  f32x4 acc[4][4] = {};
  const int nkt = Kdim >> 5;

  for (int t = 0; t < nkt; ++t){
    const int ktE = t << 5;
    #pragma unroll
    for (int j = 0; j < 2; ++j){
      const int idx = (w << 1) + j;               // 0..7
      const int row = (idx << 4) + s16;           // 0..127
      gload_lds16(A  + (size_t)(m0 + row) * Kdim + ktE + sc4 * 8, &As[idx * 512]);
      gload_lds16(Bt + (size_t)(n0 + row) * Kdim + ktE + sc4 * 8, &Bs[idx * 512]);
    }
    __syncthreads();   // drains vmcnt: staging complete

    const int ksw = (kseg ^ ((lrow >> 1) & 3)) << 3; // conflict-free slot swizzle
    bf16x8 af[4], bfr[4];
    #pragma unroll
    for (int mi = 0; mi < 4; ++mi)
      af[mi] = *(const bf16x8*)&As[(wm * 64 + mi * 16 + lrow) * 32 + ksw];
    #pragma unroll
    for (int ni = 0; ni < 4; ++ni)
      bfr[ni] = *(const bf16x8*)&Bs[(wn * 64 + ni * 16 + lrow) * 32 + ksw];
    #pragma unroll
    for (int mi = 0; mi < 4; ++mi)
      #pragma unroll
      for (int ni = 0; ni < 4; ++ni)
        acc[mi][ni] = mfma16(af[mi], bfr[ni], acc[mi][ni]);

    __syncthreads();   // guard LDS reuse by next stage
  }

  if (MODE == 1){
    // fp32 direct stores: 4B x 16 lanes = 64B full lines
    #pragma unroll
    for (int ni = 0; ni < 4; ++ni){
      const int gc = n0 + wn * 64 + ni * 16 + lrow;
      const float bv = bias[gc];
      #pragma unroll
      for (int mi = 0; mi < 4; ++mi)
        #pragma unroll
        for (int r_ = 0; r_ < 4; ++r_){
          const int gr = m0 + wm * 64 + mi * 16 + (kseg << 2) + r_;
          outF[(size_t)gr * Ndim + gc] = acc[mi][ni][r_] + bv;
        }
    }
  } else if (MODE == 0){
    // LDS-transposed coalesced bf16 epilogue (wave-private 1024-elem region)
    unsigned short* Ls = (unsigned short*)As + w * 1024;
    const int region = (n0 + wn * 64) >> 10;                 // 0=q,1=k,2=v (wave-uniform)
    const int hh = ((n0 + wn * 64) & (DMODEL - 1)) >> 6;     // head
    unsigned short* dst = region == 0 ? qo : (region == 1 ? ko : vo);
    const float mul = region == 0 ? QSCALE : 1.0f;
    float bv[4];
    #pragma unroll
    for (int ni = 0; ni < 4; ++ni) bv[ni] = bias[n0 + wn * 64 + ni * 16 + lrow];
    const int r2 = lane >> 2, c2 = lane & 3;
    #pragma unroll
    for (int mi = 0; mi < 4; ++mi){
      #pragma unroll
      for (int ni = 0; ni < 4; ++ni)
        #pragma unroll
        for (int r_ = 0; r_ < 4; ++r_){
          const int row = (kseg << 2) + r_;
          const int col = (ni * 16 + lrow) ^ (kseg << 3);    // bank-spread swizzle
          Ls[row * 64 + col] = f2bf((acc[mi][ni][r_] + bv[ni]) * mul);
        }
      __syncthreads();
      const int grr = m0 + wm * 64 + mi * 16 + r2;
      const int bb = grr >> 11, tt = grr & (TSEQ - 1);
      unsigned short* drow = dst + (((size_t)bb * NHEAD + hh) * TSEQ + tt) * 64;
      #pragma unroll
      for (int half = 0; half < 2; ++half){
        const int d0 = c2 * 8 + half * 32;
        const int colb = d0 ^ ((r2 >> 2) << 3);
        *(bf16x8*)&drow[d0] = *(const bf16x8*)&Ls[r2 * 64 + colb];
      }
    }
  } else {
    // MODE 2 fallback: old scatter epilogue (v direct to vT)
    #pragma unroll
    for (int ni = 0; ni < 4; ++ni){
      const int gc = n0 + wn * 64 + ni * 16 + lrow;
      const float bv = bias[gc];
      #pragma unroll
      for (int mi = 0; mi < 4; ++mi)
        #pragma unroll
        for (int r_ = 0; r_ < 4; ++r_){
          const int gr = m0 + wm * 64 + mi * 16 + (kseg << 2) + r_;
          float val = acc[mi][ni][r_] + bv;
          const int bb = gr >> 11, tt = gr & (TSEQ - 1);
          const int c = gc & (DMODEL - 1), hh = c >> 6, d = c & 63;
          const size_t off = (((size_t)bb * NHEAD + hh) * TSEQ + tt) * 64 + d;
          if (gc < DMODEL)          qo[off] = f2bf(val * QSCALE);
          else if (gc < 2 * DMODEL) ko[off] = f2bf(val);
          else vo[(((size_t)bb * NHEAD + hh) * 64 + d) * TSEQ + tt] = f2bf(val);
        }
    }
  }
}

// ---------------- causal flash attention, 32x32 swapped-QK^T structure ----------------
__global__ __launch_bounds__(256, 2) void attn_kernel(
    const unsigned short* __restrict__ qg,   // [BH][T][64], pre-scaled by 0.125*log2e
    const unsigned short* __restrict__ kg,   // [BH][T][64]
    const unsigned short* __restrict__ vTg,  // [BH][64][T]
    unsigned short* __restrict__ y)          // [B*T][1024] bf16
{
  __shared__ unsigned short Ks[2][64 * 64];
  __shared__ unsigned short Vs[2][64 * 64];

  const int nwg  = gridDim.x * gridDim.y;    // 512
  const int orig = blockIdx.y * gridDim.x + blockIdx.x;
  const int swz  = (orig & 7) * (nwg >> 3) + (orig >> 3);
  const int p  = swz & 7;
  const int bh = swz >> 3;
  const int bb = bh >> 4, h = bh & (NHEAD - 1);

  const int tid = threadIdx.x, lane = tid & 63, w = tid >> 6;
  const int l31 = lane & 31, hi = lane >> 5;
  const int sr8 = lane >> 3, sc8 = lane & 7;

  auto stage = [&](int buf, int kb){
    const int kt0 = kb * 64;
    #pragma unroll
    for (int j = 0; j < 2; ++j){
      const int idx = (w << 1) + j;
      const int r   = (idx << 3) + sr8;
      const int c8  = sc8 ^ (r & 7);
      gload_lds16(kg  + ((size_t)bh * TSEQ + kt0 + r) * 64 + c8 * 8, &Ks[buf][idx * 512]);
      gload_lds16(vTg + ((size_t)bh * 64 + r) * TSEQ + kt0 + c8 * 8, &Vs[buf][idx * 512]);
    }
  };

  int cur = 0;
  for (int hf = 0; hf < 2; ++hf){
    const int qt  = hf ? (15 - p) : p;
    const int q0w = qt * 128 + w * 32;
    const int q   = q0w + l31;
    const int nkv = 2 * qt + 2;

    bf16x8 qf[4];
    {
      const unsigned short* qp = qg + ((size_t)bh * TSEQ + q) * 64 + hi * 8;
      #pragma unroll
      for (int dk = 0; dk < 4; ++dk) qf[dk] = *(const bf16x8*)(qp + dk * 16);
    }

    f32x16 o0 = {}, o1 = {};
    float m_run = -1e30f, l_run = 0.f;

    stage(cur, 0);
    __syncthreads();

    for (int kb = 0; kb < nkv; ++kb){
      const int kt0 = kb * 64;
      if (kb + 1 < nkv) stage(cur ^ 1, kb + 1);

      if (kt0 <= q0w + 31){
        f32x16 s0 = {}, s1 = {};
        #pragma unroll
        for (int dk = 0; dk < 4; ++dk){
          const int c = ((dk << 1) + hi) ^ (l31 & 7);
          bf16x8 k0 = *(const bf16x8*)&Ks[cur][ l31       * 64 + c * 8];
          bf16x8 k1 = *(const bf16x8*)&Ks[cur][(l31 + 32) * 64 + c * 8];
          s0 = mfma32(k0, qf[dk], s0);
          s1 = mfma32(k1, qf[dk], s1);
        }
        if (kt0 + 63 > q0w){
          #pragma unroll
          for (int r = 0; r < 16; ++r){
            const int key = kt0 + (r & 3) + 8 * (r >> 2) + 4 * hi;
            if (key      > q) s0[r] = -1e30f;
            if (key + 32 > q) s1[r] = -1e30f;
          }
        }
        float t16[16];
        #pragma unroll
        for (int i = 0; i < 16; ++i) t16[i] = fmaxf(s0[i], s1[i]);
        #pragma unroll
        for (int st = 8; st >= 1; st >>= 1)
          #pragma unroll
          for (int i = 0; i < 16; ++i) if (i < st) t16[i] = fmaxf(t16[i], t16[i + st]);
        float mx = fmaxf(t16[0], __shfl_xor(t16[0], 32));
        const float mnew = fmaxf(m_run, mx);
        const float resc = __builtin_amdgcn_exp2f(m_run - mnew);
        m_run = mnew;
        float sa = 0.f, sb = 0.f, sc_ = 0.f, sd = 0.f;
        #pragma unroll
        for (int i = 0; i < 4; ++i){
          s0[i]      = __builtin_amdgcn_exp2f(s0[i]      - mnew); sa += s0[i];
          s0[i + 4]  = __builtin_amdgcn_exp2f(s0[i + 4]  - mnew); sb += s0[i + 4];
          s0[i + 8]  = __builtin_amdgcn_exp2f(s0[i + 8]  - mnew); sc_ += s0[i + 8];
          s0[i + 12] = __builtin_amdgcn_exp2f(s0[i + 12] - mnew); sd += s0[i + 12];
          s1[i]      = __builtin_amdgcn_exp2f(s1[i]      - mnew); sa += s1[i];
          s1[i + 4]  = __builtin_amdgcn_exp2f(s1[i + 4]  - mnew); sb += s1[i + 4];
          s1[i + 8]  = __builtin_amdgcn_exp2f(s1[i + 8]  - mnew); sc_ += s1[i + 8];
          s1[i + 12] = __builtin_amdgcn_exp2f(s1[i + 12] - mnew); sd += s1[i + 12];
        }
        float sum = (sa + sb) + (sc_ + sd);
        sum += __shfl_xor(sum, 32);
        l_run = l_run * resc + sum;
        #pragma unroll
        for (int r = 0; r < 16; ++r){ o0[r] *= resc; o1[r] *= resc; }

        bf16x8 pf[4];
        #pragma unroll
        for (int kc = 0; kc < 4; ++kc){
          const int base = (kc & 1) * 8;
          float p0,p1,p2,p3,p4,p5,p6,p7;
          if (kc < 2){ p0=s0[base];p1=s0[base+1];p2=s0[base+2];p3=s0[base+3];
                       p4=s0[base+4];p5=s0[base+5];p6=s0[base+6];p7=s0[base+7]; }
          else       { p0=s1[base];p1=s1[base+1];p2=s1[base+2];p3=s1[base+3];
                       p4=s1[base+4];p5=s1[base+5];p6=s1[base+6];p7=s1[base+7]; }
          unsigned X0 = cvt_pk_bf16(p0, p1), X1 = cvt_pk_bf16(p2, p3);
          unsigned Y0 = cvt_pk_bf16(p4, p5), Y1 = cvt_pk_bf16(p6, p7);
          auto sA = __builtin_amdgcn_permlane32_swap(X0, Y0, false, false);
          auto sB = __builtin_amdgcn_permlane32_swap(X1, Y1, false, false);
          union { unsigned u[4]; bf16x8 v; } fr;
          fr.u[0] = sA[0]; fr.u[1] = sB[0]; fr.u[2] = sA[1]; fr.u[3] = sB[1];
          pf[kc] = fr.v;
        }
        #pragma unroll
        for (int kc = 0; kc < 4; ++kc){
          const int c0 = ((kc << 1) + hi) ^ (l31 & 7);
          bf16x8 v0 = *(const bf16x8*)&Vs[cur][ l31       * 64 + c0 * 8];
          bf16x8 v1 = *(const bf16x8*)&Vs[cur][(l31 + 32) * 64 + c0 * 8];
          o0 = mfma32(v0, pf[kc], o0);
          o1 = mfma32(v1, pf[kc], o1);
        }
      }
      __syncthreads();
      cur ^= 1;
    }

    const float rl = 1.0f / l_run;
    unsigned short* yrow = y + ((size_t)bb * TSEQ + q) * DMODEL + h * 64;
    #pragma unroll
    for (int i = 0; i < 8; ++i){
      const int r = 2 * i;
      const int d = (r & 3) + 8 * (r >> 2) + 4 * hi;
      unsigned pk0 = (unsigned)f2bf(o0[r] * rl) | ((unsigned)f2bf(o0[r + 1] * rl) << 16);
      unsigned pk1 = (unsigned)f2bf(o1[r] * rl) | ((unsigned)f2bf(o1[r + 1] * rl) << 16);
      *(unsigned*)(yrow + d)      = pk0;
      *(unsigned*)(yrow + d + 32) = pk1;
    }
  }
}

extern "C" void kernel_launch(void* const* d_in, const int* in_sizes, int n_in,
                              void* d_out, int out_size, void* d_ws, size_t ws_size,
                              hipStream_t stream) {
  const float* x    = (const float*)d_in[0];
  const float* Wqkv = (const float*)d_in[1];
  const float* bqkv = (const float*)d_in[2];
  const float* Wo   = (const float*)d_in[3];
  const float* bo   = (const float*)d_in[4];
  float* out = (float*)d_out;

  char* ws = (char*)d_ws;
  unsigned short* x_bf   = (unsigned short*)(ws);
  unsigned short* Wqkv_t = (unsigned short*)(ws + (16u << 20));
  unsigned short* Wo_t   = (unsigned short*)(ws + (22u << 20));
  unsigned short* q_ws   = (unsigned short*)(ws + (24u << 20));
  unsigned short* k_ws   = (unsigned short*)(ws + (40u << 20));
  unsigned short* v_ws   = (unsigned short*)(ws + (56u << 20));
  unsigned short* vT_ws  = (unsigned short*)(ws + (72u << 20));
  unsigned short* y_bf   = x_bf;   // x_bf dead after GEMM1

  cast_x_kernel<<<8192, 256, 0, stream>>>(x, x_bf);
  transpose_cast_kernel<<<dim3(96, 32), 256, 0, stream>>>(Wqkv, Wqkv_t, 1024, 3072);
  transpose_cast_kernel<<<dim3(32, 32), 256, 0, stream>>>(Wo, Wo_t, 1024, 1024);

  if (ws_size >= ((size_t)88 << 20)) {
    gemm_bf16_kernel<0><<<dim3(24, 64), 256, 0, stream>>>(x_bf, Wqkv_t, bqkv,
                                                          nullptr, q_ws, k_ws, v_ws, 1024, 3072);
    transpose_v_kernel<<<dim3(64, 64), 256, 0, stream>>>(v_ws, vT_ws);
  } else {
    vT_ws = v_ws;
    gemm_bf16_kernel<2><<<dim3(24, 64), 256, 0, stream>>>(x_bf, Wqkv_t, bqkv,
                                                          nullptr, q_ws, k_ws, vT_ws, 1024, 3072);
  }
  attn_kernel<<<dim3(8, 64), 256, 0, stream>>>(q_ws, k_ws, vT_ws, y_bf);
  gemm_bf16_kernel<1><<<dim3(8, 64), 256, 0, stream>>>(y_bf, Wo_t, bo,
                                                       out, nullptr, nullptr, nullptr, 1024, 1024);
}

// Round 6
// 179.530 us; speedup vs baseline: 3.5180x; 1.0386x over previous
//
#include <hip/hip_runtime.h>
#include <hip/hip_bf16.h>

// Problem constants
#define TSEQ   2048
#define NHEAD  16
#define DMODEL 1024

typedef __attribute__((ext_vector_type(8)))  __bf16 bf16x8;
typedef __attribute__((ext_vector_type(4)))  float  f32x4;
typedef __attribute__((ext_vector_type(16))) float  f32x16;

typedef const void __attribute__((address_space(1))) * gptr_as1;
typedef void       __attribute__((address_space(3))) * lptr_as3;

static __device__ __forceinline__ void gload_lds16(const void* g, void* l){
  __builtin_amdgcn_global_load_lds((gptr_as1)g, (lptr_as3)l, 16, 0, 0);
}

static __device__ __forceinline__ unsigned short f2bf(float f){
  union { float f; unsigned u; } v; v.f = f;
  return (unsigned short)((v.u + 0x7FFFu + ((v.u >> 16) & 1u)) >> 16);
}

static __device__ __forceinline__ f32x4 mfma16(bf16x8 a, bf16x8 b, f32x4 c){
  return __builtin_amdgcn_mfma_f32_16x16x32_bf16(a, b, c, 0, 0, 0);
}
static __device__ __forceinline__ f32x16 mfma32(bf16x8 a, bf16x8 b, f32x16 c){
  return __builtin_amdgcn_mfma_f32_32x32x16_bf16(a, b, c, 0, 0, 0);
}
static __device__ __forceinline__ unsigned cvt_pk_bf16(float lo, float hi){
  unsigned r;
  asm("v_cvt_pk_bf16_f32 %0, %1, %2" : "=v"(r) : "v"(lo), "v"(hi));
  return r;
}

// fold softmax scale AND log2(e) into q: exp(s) == exp2(s')
#define QSCALE 0.18033688011112042f   // 0.125 * log2(e)

// ---------------- cast x (f32 -> bf16), vectorized ----------------
__global__ __launch_bounds__(256) void cast_x_kernel(const float* __restrict__ in,
                                                     unsigned short* __restrict__ out){
  int i = blockIdx.x * 256 + threadIdx.x;
  float4 v = *(const float4*)(in + (size_t)i * 4);
  ushort4 o;
  o.x = f2bf(v.x); o.y = f2bf(v.y); o.z = f2bf(v.z); o.w = f2bf(v.w);
  *(ushort4*)(out + (size_t)i * 4) = o;
}

// -------- transpose + cast: in [K][N] f32  ->  out [N][K] bf16 --------
__global__ __launch_bounds__(256) void transpose_cast_kernel(const float* __restrict__ in,
                                                             unsigned short* __restrict__ out,
                                                             int K, int N){
  __shared__ float tile[32][33];
  int n0 = blockIdx.x * 32, k0 = blockIdx.y * 32;
  int tx = threadIdx.x & 31, ty = threadIdx.x >> 5;
  #pragma unroll
  for (int r = ty; r < 32; r += 8)
    tile[r][tx] = in[(size_t)(k0 + r) * N + n0 + tx];
  __syncthreads();
  #pragma unroll
  for (int r = ty; r < 32; r += 8)
    out[(size_t)(n0 + r) * K + k0 + tx] = f2bf(tile[tx][r]);
}

// -------- v transpose: [BH][T][64] -> [BH][64][T], LDS-free --------
__global__ __launch_bounds__(256) void transpose_v_kernel(
    const unsigned short* __restrict__ vin,
    unsigned short* __restrict__ vT){
  const int bh = blockIdx.y;
  const int t0 = blockIdx.x * 32 + (threadIdx.x >> 6) * 8;
  const int d  = threadIdx.x & 63;
  const unsigned short* src = vin + ((size_t)bh * TSEQ + t0) * 64 + d;
  ushort4 a, b;
  a.x = src[0];   a.y = src[64];  a.z = src[128]; a.w = src[192];
  b.x = src[256]; b.y = src[320]; b.z = src[384]; b.w = src[448];
  unsigned short* dst = vT + ((size_t)bh * 64 + d) * TSEQ + t0;
  *(ushort4*)dst       = a;
  *(ushort4*)(dst + 4) = b;
}

// ------------- bf16 MFMA GEMM: counted-vmcnt 2-phase pipeline -------------
// BM=128, BN=256, BK=64; 512 threads = 8 waves (2M x 4N), per-wave 64x64 out.
// LDS: 2 slots x (A 128x64 + B 256x64) bf16 = 96 KB; 1 block/CU.
// Per K-tile: P1{read 16 frags, 16 MFMA, lgkm0, bar} P2{stage kt+2, 16 MFMA, vmcnt(6), bar}.
// MODE 0: qkv -> q,k,v [BH][T][64], LDS-transposed coalesced epilogue
// MODE 1: out projection -> fp32 out [M][N]
// MODE 2: qkv fallback -> q,k [BH][T][64], v scattered direct to vT
template<int MODE>
__global__ __launch_bounds__(512, 2) void gemm_bf16_kernel(
    const unsigned short* __restrict__ A,
    const unsigned short* __restrict__ Bt,
    const float* __restrict__ bias,
    float* __restrict__ outF,
    unsigned short* __restrict__ qo,
    unsigned short* __restrict__ ko,
    unsigned short* __restrict__ vo,
    int Kdim, int Ndim)
{
  __shared__ unsigned short As[2][128 * 64];   // 32 KB
  __shared__ unsigned short Bs[2][256 * 64];   // 64 KB

  const int nwg  = gridDim.x * gridDim.y;
  const int orig = blockIdx.y * gridDim.x + blockIdx.x;
  const int swz  = (orig & 7) * (nwg >> 3) + (orig >> 3);
  const int n0 = (swz % gridDim.x) * 256;
  const int m0 = (swz / gridDim.x) * 128;

  const int tid = threadIdx.x, lane = tid & 63, w = tid >> 6;
  const int wm = w >> 2, wn = w & 3;
  const int lrow = lane & 15, kseg = (lane >> 4) & 3;
  const int sr8 = lane >> 3, sc8 = lane & 7;

  auto stage = [&](int slot, int ktile){
    const unsigned short* Ab = A  + (size_t)m0 * Kdim + ktile * 64;
    const unsigned short* Bb = Bt + (size_t)n0 * Kdim + ktile * 64;
    #pragma unroll
    for (int j = 0; j < 2; ++j){
      const int row = w * 16 + j * 8 + sr8;                 // 0..127
      gload_lds16(Ab + (size_t)row * Kdim + ((sc8 ^ (row & 7)) << 3),
                  &As[slot][(w * 2 + j) * 512]);
    }
    #pragma unroll
    for (int j = 0; j < 4; ++j){
      const int row = w * 32 + j * 8 + sr8;                 // 0..255
      gload_lds16(Bb + (size_t)row * Kdim + ((sc8 ^ (row & 7)) << 3),
                  &Bs[slot][(w * 4 + j) * 512]);
    }
  };

  f32x4 acc[4][4] = {};
  const int NT = Kdim >> 6;

  stage(0, 0);
  stage(1, 1);
  asm volatile("s_waitcnt vmcnt(6)" ::: "memory");   // T0's 6 loads landed
  __builtin_amdgcn_s_barrier();

  for (int kt = 0; kt < NT; ++kt){
    const int slot = kt & 1;
    // ---- P1: read ALL fragments of this K-tile, compute ni 0-1 ----
    bf16x8 af[4][2], bfr[4][2];
    #pragma unroll
    for (int mi = 0; mi < 4; ++mi){
      const int row = wm * 64 + mi * 16 + lrow;
      #pragma unroll
      for (int kk = 0; kk < 2; ++kk)
        af[mi][kk] = *(const bf16x8*)&As[slot][row * 64 + ((((kk << 2) | kseg) ^ (row & 7)) << 3)];
    }
    #pragma unroll
    for (int ni = 0; ni < 4; ++ni){
      const int row = wn * 64 + ni * 16 + lrow;
      #pragma unroll
      for (int kk = 0; kk < 2; ++kk)
        bfr[ni][kk] = *(const bf16x8*)&Bs[slot][row * 64 + ((((kk << 2) | kseg) ^ (row & 7)) << 3)];
    }
    __builtin_amdgcn_s_setprio(1);
    #pragma unroll
    for (int mi = 0; mi < 4; ++mi)
      #pragma unroll
      for (int ni = 0; ni < 2; ++ni)
        #pragma unroll
        for (int kk = 0; kk < 2; ++kk)
          acc[mi][ni] = mfma16(af[mi][kk], bfr[ni][kk], acc[mi][ni]);
    __builtin_amdgcn_s_setprio(0);
    asm volatile("s_waitcnt lgkmcnt(0)" ::: "memory");  // all reads of slot done
    __builtin_amdgcn_sched_barrier(0);
    __builtin_amdgcn_s_barrier();                        // slot now free block-wide

    // ---- P2: stage T(kt+2) into freed slot, compute ni 2-3 ----
    if (kt + 2 < NT) stage(slot, kt + 2);
    __builtin_amdgcn_s_setprio(1);
    #pragma unroll
    for (int mi = 0; mi < 4; ++mi)
      #pragma unroll
      for (int ni = 2; ni < 4; ++ni)
        #pragma unroll
        for (int kk = 0; kk < 2; ++kk)
          acc[mi][ni] = mfma16(af[mi][kk], bfr[ni][kk], acc[mi][ni]);
    __builtin_amdgcn_s_setprio(0);
    if (kt < NT - 2) { asm volatile("s_waitcnt vmcnt(6)" ::: "memory"); }  // T(kt+1) landed
    else             { asm volatile("s_waitcnt vmcnt(0)" ::: "memory"); }
    __builtin_amdgcn_s_barrier();
  }

  if (MODE == 1){
    // fp32 direct stores: 4B x 16 lanes = 64B full lines
    #pragma unroll
    for (int ni = 0; ni < 4; ++ni){
      const int gc = n0 + wn * 64 + ni * 16 + lrow;
      const float bv = bias[gc];
      #pragma unroll
      for (int mi = 0; mi < 4; ++mi)
        #pragma unroll
        for (int r_ = 0; r_ < 4; ++r_){
          const int gr = m0 + wm * 64 + mi * 16 + (kseg << 2) + r_;
          outF[(size_t)gr * Ndim + gc] = acc[mi][ni][r_] + bv;
        }
    }
  } else if (MODE == 0){
    // LDS-transposed coalesced bf16 epilogue (wave-private 1024-elem region)
    unsigned short* Ls = &As[0][0] + w * 1024;
    const int region = (n0 + wn * 64) >> 10;                 // 0=q,1=k,2=v (wave-uniform)
    const int hh = ((n0 + wn * 64) & (DMODEL - 1)) >> 6;     // head
    unsigned short* dst = region == 0 ? qo : (region == 1 ? ko : vo);
    const float mul = region == 0 ? QSCALE : 1.0f;
    float bv[4];
    #pragma unroll
    for (int ni = 0; ni < 4; ++ni) bv[ni] = bias[n0 + wn * 64 + ni * 16 + lrow];
    const int r2 = lane >> 2, c2 = lane & 3;
    #pragma unroll
    for (int mi = 0; mi < 4; ++mi){
      #pragma unroll
      for (int ni = 0; ni < 4; ++ni)
        #pragma unroll
        for (int r_ = 0; r_ < 4; ++r_){
          const int row = (kseg << 2) + r_;
          const int col = (ni * 16 + lrow) ^ (kseg << 3);    // bank-spread swizzle
          Ls[row * 64 + col] = f2bf((acc[mi][ni][r_] + bv[ni]) * mul);
        }
      __syncthreads();   // wave-private data; block barrier keeps waves in lockstep (safe)
      const int grr = m0 + wm * 64 + mi * 16 + r2;
      const int bb = grr >> 11, tt = grr & (TSEQ - 1);
      unsigned short* drow = dst + (((size_t)bb * NHEAD + hh) * TSEQ + tt) * 64;
      #pragma unroll
      for (int half = 0; half < 2; ++half){
        const int d0 = c2 * 8 + half * 32;
        const int colb = d0 ^ ((r2 >> 2) << 3);
        *(bf16x8*)&drow[d0] = *(const bf16x8*)&Ls[r2 * 64 + colb];
      }
      __syncthreads();
    }
  } else {
    // MODE 2 fallback: scatter epilogue (v direct to vT)
    #pragma unroll
    for (int ni = 0; ni < 4; ++ni){
      const int gc = n0 + wn * 64 + ni * 16 + lrow;
      const float bv = bias[gc];
      #pragma unroll
      for (int mi = 0; mi < 4; ++mi)
        #pragma unroll
        for (int r_ = 0; r_ < 4; ++r_){
          const int gr = m0 + wm * 64 + mi * 16 + (kseg << 2) + r_;
          float val = acc[mi][ni][r_] + bv;
          const int bb = gr >> 11, tt = gr & (TSEQ - 1);
          const int c = gc & (DMODEL - 1), hc = c >> 6, d = c & 63;
          const size_t off = (((size_t)bb * NHEAD + hc) * TSEQ + tt) * 64 + d;
          if (gc < DMODEL)          qo[off] = f2bf(val * QSCALE);
          else if (gc < 2 * DMODEL) ko[off] = f2bf(val);
          else vo[(((size_t)bb * NHEAD + hc) * 64 + d) * TSEQ + tt] = f2bf(val);
        }
    }
  }
}

// ---------------- causal flash attention, 32x32 swapped-QK^T structure ----------------
__global__ __launch_bounds__(256, 2) void attn_kernel(
    const unsigned short* __restrict__ qg,   // [BH][T][64], pre-scaled by 0.125*log2e
    const unsigned short* __restrict__ kg,   // [BH][T][64]
    const unsigned short* __restrict__ vTg,  // [BH][64][T]
    unsigned short* __restrict__ y)          // [B*T][1024] bf16
{
  __shared__ unsigned short Ks[2][64 * 64];
  __shared__ unsigned short Vs[2][64 * 64];

  const int nwg  = gridDim.x * gridDim.y;    // 512
  const int orig = blockIdx.y * gridDim.x + blockIdx.x;
  const int swz  = (orig & 7) * (nwg >> 3) + (orig >> 3);
  const int p  = swz & 7;
  const int bh = swz >> 3;
  const int bb = bh >> 4, h = bh & (NHEAD - 1);

  const int tid = threadIdx.x, lane = tid & 63, w = tid >> 6;
  const int l31 = lane & 31, hi = lane >> 5;
  const int sr8 = lane >> 3, sc8 = lane & 7;

  auto stage = [&](int buf, int kb){
    const int kt0 = kb * 64;
    #pragma unroll
    for (int j = 0; j < 2; ++j){
      const int idx = (w << 1) + j;
      const int r   = (idx << 3) + sr8;
      const int c8  = sc8 ^ (r & 7);
      gload_lds16(kg  + ((size_t)bh * TSEQ + kt0 + r) * 64 + c8 * 8, &Ks[buf][idx * 512]);
      gload_lds16(vTg + ((size_t)bh * 64 + r) * TSEQ + kt0 + c8 * 8, &Vs[buf][idx * 512]);
    }
  };

  int cur = 0;
  for (int hf = 0; hf < 2; ++hf){
    const int qt  = hf ? (15 - p) : p;
    const int q0w = qt * 128 + w * 32;
    const int q   = q0w + l31;
    const int nkv = 2 * qt + 2;

    bf16x8 qf[4];
    {
      const unsigned short* qp = qg + ((size_t)bh * TSEQ + q) * 64 + hi * 8;
      #pragma unroll
      for (int dk = 0; dk < 4; ++dk) qf[dk] = *(const bf16x8*)(qp + dk * 16);
    }

    f32x16 o0 = {}, o1 = {};
    float m_run = -1e30f, l_run = 0.f;

    stage(cur, 0);
    __syncthreads();

    for (int kb = 0; kb < nkv; ++kb){
      const int kt0 = kb * 64;
      if (kb + 1 < nkv) stage(cur ^ 1, kb + 1);

      if (kt0 <= q0w + 31){
        f32x16 s0 = {}, s1 = {};
        #pragma unroll
        for (int dk = 0; dk < 4; ++dk){
          const int c = ((dk << 1) + hi) ^ (l31 & 7);
          bf16x8 k0 = *(const bf16x8*)&Ks[cur][ l31       * 64 + c * 8];
          bf16x8 k1 = *(const bf16x8*)&Ks[cur][(l31 + 32) * 64 + c * 8];
          s0 = mfma32(k0, qf[dk], s0);
          s1 = mfma32(k1, qf[dk], s1);
        }
        if (kt0 + 63 > q0w){
          #pragma unroll
          for (int r = 0; r < 16; ++r){
            const int key = kt0 + (r & 3) + 8 * (r >> 2) + 4 * hi;
            if (key      > q) s0[r] = -1e30f;
            if (key + 32 > q) s1[r] = -1e30f;
          }
        }
        float t16[16];
        #pragma unroll
        for (int i = 0; i < 16; ++i) t16[i] = fmaxf(s0[i], s1[i]);
        #pragma unroll
        for (int st = 8; st >= 1; st >>= 1)
          #pragma unroll
          for (int i = 0; i < 16; ++i) if (i < st) t16[i] = fmaxf(t16[i], t16[i + st]);
        float mx = fmaxf(t16[0], __shfl_xor(t16[0], 32));
        const float mnew = fmaxf(m_run, mx);
        const float resc = __builtin_amdgcn_exp2f(m_run - mnew);
        m_run = mnew;
        float sa = 0.f, sb = 0.f, sc_ = 0.f, sd = 0.f;
        #pragma unroll
        for (int i = 0; i < 4; ++i){
          s0[i]      = __builtin_amdgcn_exp2f(s0[i]      - mnew); sa += s0[i];
          s0[i + 4]  = __builtin_amdgcn_exp2f(s0[i + 4]  - mnew); sb += s0[i + 4];
          s0[i + 8]  = __builtin_amdgcn_exp2f(s0[i + 8]  - mnew); sc_ += s0[i + 8];
          s0[i + 12] = __builtin_amdgcn_exp2f(s0[i + 12] - mnew); sd += s0[i + 12];
          s1[i]      = __builtin_amdgcn_exp2f(s1[i]      - mnew); sa += s1[i];
          s1[i + 4]  = __builtin_amdgcn_exp2f(s1[i + 4]  - mnew); sb += s1[i + 4];
          s1[i + 8]  = __builtin_amdgcn_exp2f(s1[i + 8]  - mnew); sc_ += s1[i + 8];
          s1[i + 12] = __builtin_amdgcn_exp2f(s1[i + 12] - mnew); sd += s1[i + 12];
        }
        float sum = (sa + sb) + (sc_ + sd);
        sum += __shfl_xor(sum, 32);
        l_run = l_run * resc + sum;
        #pragma unroll
        for (int r = 0; r < 16; ++r){ o0[r] *= resc; o1[r] *= resc; }

        bf16x8 pf[4];
        #pragma unroll
        for (int kc = 0; kc < 4; ++kc){
          const int base = (kc & 1) * 8;
          float p0,p1,p2,p3,p4,p5,p6,p7;
          if (kc < 2){ p0=s0[base];p1=s0[base+1];p2=s0[base+2];p3=s0[base+3];
                       p4=s0[base+4];p5=s0[base+5];p6=s0[base+6];p7=s0[base+7]; }
          else       { p0=s1[base];p1=s1[base+1];p2=s1[base+2];p3=s1[base+3];
                       p4=s1[base+4];p5=s1[base+5];p6=s1[base+6];p7=s1[base+7]; }
          unsigned X0 = cvt_pk_bf16(p0, p1), X1 = cvt_pk_bf16(p2, p3);
          unsigned Y0 = cvt_pk_bf16(p4, p5), Y1 = cvt_pk_bf16(p6, p7);
          auto sA = __builtin_amdgcn_permlane32_swap(X0, Y0, false, false);
          auto sB = __builtin_amdgcn_permlane32_swap(X1, Y1, false, false);
          union { unsigned u[4]; bf16x8 v; } fr;
          fr.u[0] = sA[0]; fr.u[1] = sB[0]; fr.u[2] = sA[1]; fr.u[3] = sB[1];
          pf[kc] = fr.v;
        }
        #pragma unroll
        for (int kc = 0; kc < 4; ++kc){
          const int c0 = ((kc << 1) + hi) ^ (l31 & 7);
          bf16x8 v0 = *(const bf16x8*)&Vs[cur][ l31       * 64 + c0 * 8];
          bf16x8 v1 = *(const bf16x8*)&Vs[cur][(l31 + 32) * 64 + c0 * 8];
          o0 = mfma32(v0, pf[kc], o0);
          o1 = mfma32(v1, pf[kc], o1);
        }
      }
      __syncthreads();
      cur ^= 1;
    }

    const float rl = 1.0f / l_run;
    unsigned short* yrow = y + ((size_t)bb * TSEQ + q) * DMODEL + h * 64;
    #pragma unroll
    for (int i = 0; i < 8; ++i){
      const int r = 2 * i;
      const int d = (r & 3) + 8 * (r >> 2) + 4 * hi;
      unsigned pk0 = (unsigned)f2bf(o0[r] * rl) | ((unsigned)f2bf(o0[r + 1] * rl) << 16);
      unsigned pk1 = (unsigned)f2bf(o1[r] * rl) | ((unsigned)f2bf(o1[r + 1] * rl) << 16);
      *(unsigned*)(yrow + d)      = pk0;
      *(unsigned*)(yrow + d + 32) = pk1;
    }
  }
}

extern "C" void kernel_launch(void* const* d_in, const int* in_sizes, int n_in,
                              void* d_out, int out_size, void* d_ws, size_t ws_size,
                              hipStream_t stream) {
  const float* x    = (const float*)d_in[0];
  const float* Wqkv = (const float*)d_in[1];
  const float* bqkv = (const float*)d_in[2];
  const float* Wo   = (const float*)d_in[3];
  const float* bo   = (const float*)d_in[4];
  float* out = (float*)d_out;

  char* ws = (char*)d_ws;
  unsigned short* x_bf   = (unsigned short*)(ws);
  unsigned short* Wqkv_t = (unsigned short*)(ws + (16u << 20));
  unsigned short* Wo_t   = (unsigned short*)(ws + (22u << 20));
  unsigned short* q_ws   = (unsigned short*)(ws + (24u << 20));
  unsigned short* k_ws   = (unsigned short*)(ws + (40u << 20));
  unsigned short* v_ws   = (unsigned short*)(ws + (56u << 20));
  unsigned short* vT_ws  = (unsigned short*)(ws + (72u << 20));
  unsigned short* y_bf   = x_bf;   // x_bf dead after GEMM1

  cast_x_kernel<<<8192, 256, 0, stream>>>(x, x_bf);
  transpose_cast_kernel<<<dim3(96, 32), 256, 0, stream>>>(Wqkv, Wqkv_t, 1024, 3072);
  transpose_cast_kernel<<<dim3(32, 32), 256, 0, stream>>>(Wo, Wo_t, 1024, 1024);

  if (ws_size >= ((size_t)88 << 20)) {
    gemm_bf16_kernel<0><<<dim3(12, 64), 512, 0, stream>>>(x_bf, Wqkv_t, bqkv,
                                                          nullptr, q_ws, k_ws, v_ws, 1024, 3072);
    transpose_v_kernel<<<dim3(64, 64), 256, 0, stream>>>(v_ws, vT_ws);
  } else {
    vT_ws = v_ws;
    gemm_bf16_kernel<2><<<dim3(12, 64), 512, 0, stream>>>(x_bf, Wqkv_t, bqkv,
                                                          nullptr, q_ws, k_ws, vT_ws, 1024, 3072);
  }
  attn_kernel<<<dim3(8, 64), 256, 0, stream>>>(q_ws, k_ws, vT_ws, y_bf);
  gemm_bf16_kernel<1><<<dim3(4, 64), 512, 0, stream>>>(y_bf, Wo_t, bo,
                                                       out, nullptr, nullptr, nullptr, 1024, 1024);
}

// Round 8
// 177.223 us; speedup vs baseline: 3.5638x; 1.0130x over previous
//
#include <hip/hip_runtime.h>
#include <hip/hip_bf16.h>

// Problem constants
#define TSEQ   2048
#define NHEAD  16
#define DMODEL 1024

typedef __attribute__((ext_vector_type(8)))  __bf16 bf16x8;
typedef __attribute__((ext_vector_type(4)))  float  f32x4;
typedef __attribute__((ext_vector_type(16))) float  f32x16;

typedef const void __attribute__((address_space(1))) * gptr_as1;
typedef void       __attribute__((address_space(3))) * lptr_as3;

static __device__ __forceinline__ void gload_lds16(const void* g, void* l){
  __builtin_amdgcn_global_load_lds((gptr_as1)g, (lptr_as3)l, 16, 0, 0);
}

static __device__ __forceinline__ unsigned short f2bf(float f){
  union { float f; unsigned u; } v; v.f = f;
  return (unsigned short)((v.u + 0x7FFFu + ((v.u >> 16) & 1u)) >> 16);
}

static __device__ __forceinline__ f32x4 mfma16(bf16x8 a, bf16x8 b, f32x4 c){
  return __builtin_amdgcn_mfma_f32_16x16x32_bf16(a, b, c, 0, 0, 0);
}
static __device__ __forceinline__ f32x16 mfma32(bf16x8 a, bf16x8 b, f32x16 c){
  return __builtin_amdgcn_mfma_f32_32x32x16_bf16(a, b, c, 0, 0, 0);
}
static __device__ __forceinline__ unsigned cvt_pk_bf16(float lo, float hi){
  unsigned r;
  asm("v_cvt_pk_bf16_f32 %0, %1, %2" : "=v"(r) : "v"(lo), "v"(hi));
  return r;
}

// fold softmax scale AND log2(e) into q: exp(s) == exp2(s')
#define QSCALE 0.18033688011112042f   // 0.125 * log2(e)

// ---------------- cast x (f32 -> bf16), vectorized ----------------
__global__ __launch_bounds__(256) void cast_x_kernel(const float* __restrict__ in,
                                                     unsigned short* __restrict__ out){
  int i = blockIdx.x * 256 + threadIdx.x;
  float4 v = *(const float4*)(in + (size_t)i * 4);
  ushort4 o;
  o.x = f2bf(v.x); o.y = f2bf(v.y); o.z = f2bf(v.z); o.w = f2bf(v.w);
  *(ushort4*)(out + (size_t)i * 4) = o;
}

// -------- transpose + cast: in [K][N] f32  ->  out [N][K] bf16 --------
__global__ __launch_bounds__(256) void transpose_cast_kernel(const float* __restrict__ in,
                                                             unsigned short* __restrict__ out,
                                                             int K, int N){
  __shared__ float tile[32][33];
  int n0 = blockIdx.x * 32, k0 = blockIdx.y * 32;
  int tx = threadIdx.x & 31, ty = threadIdx.x >> 5;
  #pragma unroll
  for (int r = ty; r < 32; r += 8)
    tile[r][tx] = in[(size_t)(k0 + r) * N + n0 + tx];
  __syncthreads();
  #pragma unroll
  for (int r = ty; r < 32; r += 8)
    out[(size_t)(n0 + r) * K + k0 + tx] = f2bf(tile[tx][r]);
}

// ------------- bf16 MFMA GEMM: counted-vmcnt 2-phase, BK=32, 2 blocks/CU -------------
// BM=128, BN=256, BK=32; 512 threads = 8 waves (2M x 4N), per-wave 64x64 out.
// LDS: 2 slots x (A 128x32 + B 256x32) bf16 = 48 KB -> 2 blocks/CU (16 waves/CU).
// One gload_lds instr = 1 KB = 512 ushorts = 16 rows of 32 -> dest stride 512. (R7 bug: was 1024, OOB.)
// MODE 0: qkv -> q,k,v [BH][T][64], LDS-transposed coalesced epilogue
// MODE 1: out projection -> fp32 out [M][N]
template<int MODE>
__global__ __launch_bounds__(512, 4) void gemm_bf16_kernel(
    const unsigned short* __restrict__ A,
    const unsigned short* __restrict__ Bt,
    const float* __restrict__ bias,
    float* __restrict__ outF,
    unsigned short* __restrict__ qo,
    unsigned short* __restrict__ ko,
    unsigned short* __restrict__ vo,
    int Kdim, int Ndim)
{
  __shared__ unsigned short As[2][128 * 32];   // 8 KB x2
  __shared__ unsigned short Bs[2][256 * 32];   // 16 KB x2

  const int nwg  = gridDim.x * gridDim.y;
  const int orig = blockIdx.y * gridDim.x + blockIdx.x;
  const int swz  = (orig & 7) * (nwg >> 3) + (orig >> 3);
  const int n0 = (swz % gridDim.x) * 256;
  const int m0 = (swz / gridDim.x) * 128;

  const int tid = threadIdx.x, lane = tid & 63, w = tid >> 6;
  const int wm = w >> 2, wn = w & 3;
  const int lrow = lane & 15, kseg = (lane >> 4) & 3;
  const int s16 = lane >> 2;                       // staging row within 16-row slab
  const int sc4 = (lane & 3) ^ ((s16 >> 1) & 3);   // pre-swizzled source chunk (R5-verified)

  auto stage = [&](int slot, int ktile){
    const unsigned short* Ab = A  + (size_t)m0 * Kdim + ktile * 32;
    const unsigned short* Bb = Bt + (size_t)n0 * Kdim + ktile * 32;
    {
      const int row = (w << 4) + s16;              // 0..127
      gload_lds16(Ab + (size_t)row * Kdim + sc4 * 8, &As[slot][w * 512]);
    }
    #pragma unroll
    for (int j = 0; j < 2; ++j){
      const int row = (w << 5) + (j << 4) + s16;   // 0..255
      gload_lds16(Bb + (size_t)row * Kdim + sc4 * 8, &Bs[slot][(w * 2 + j) * 512]);
    }
  };

  f32x4 acc[4][4] = {};
  const int NT = Kdim >> 5;

  stage(0, 0);
  stage(1, 1);
  asm volatile("s_waitcnt vmcnt(3)" ::: "memory");   // T0's 3 loads landed
  __builtin_amdgcn_s_barrier();

  for (int kt = 0; kt < NT; ++kt){
    const int slot = kt & 1;
    // ---- P1: read all 8 fragments, compute ni 0-1 ----
    const int ksw = (kseg ^ ((lrow >> 1) & 3)) << 3;   // conflict-free slot swizzle
    bf16x8 af[4], bfr[4];
    #pragma unroll
    for (int mi = 0; mi < 4; ++mi)
      af[mi] = *(const bf16x8*)&As[slot][(wm * 64 + mi * 16 + lrow) * 32 + ksw];
    #pragma unroll
    for (int ni = 0; ni < 4; ++ni)
      bfr[ni] = *(const bf16x8*)&Bs[slot][(wn * 64 + ni * 16 + lrow) * 32 + ksw];
    __builtin_amdgcn_s_setprio(1);
    #pragma unroll
    for (int mi = 0; mi < 4; ++mi)
      #pragma unroll
      for (int ni = 0; ni < 2; ++ni)
        acc[mi][ni] = mfma16(af[mi], bfr[ni], acc[mi][ni]);
    __builtin_amdgcn_s_setprio(0);
    asm volatile("s_waitcnt lgkmcnt(0)" ::: "memory");  // all reads of slot done
    __builtin_amdgcn_sched_barrier(0);
    __builtin_amdgcn_s_barrier();                        // slot now free block-wide

    // ---- P2: stage T(kt+2) into freed slot, compute ni 2-3 ----
    if (kt + 2 < NT) stage(slot, kt + 2);
    __builtin_amdgcn_s_setprio(1);
    #pragma unroll
    for (int mi = 0; mi < 4; ++mi)
      #pragma unroll
      for (int ni = 2; ni < 4; ++ni)
        acc[mi][ni] = mfma16(af[mi], bfr[ni], acc[mi][ni]);
    __builtin_amdgcn_s_setprio(0);
    if (kt < NT - 2) { asm volatile("s_waitcnt vmcnt(3)" ::: "memory"); }  // T(kt+1) landed
    else             { asm volatile("s_waitcnt vmcnt(0)" ::: "memory"); }
    __builtin_amdgcn_s_barrier();
  }

  if (MODE == 1){
    // fp32 direct stores: 4B x 16 lanes = 64B full lines
    #pragma unroll
    for (int ni = 0; ni < 4; ++ni){
      const int gc = n0 + wn * 64 + ni * 16 + lrow;
      const float bv = bias[gc];
      #pragma unroll
      for (int mi = 0; mi < 4; ++mi)
        #pragma unroll
        for (int r_ = 0; r_ < 4; ++r_){
          const int gr = m0 + wm * 64 + mi * 16 + (kseg << 2) + r_;
          outF[(size_t)gr * Ndim + gc] = acc[mi][ni][r_] + bv;
        }
    }
  } else {
    // LDS-transposed coalesced bf16 epilogue (wave-private 1024-elem region)
    unsigned short* Ls = &As[0][0] + w * 1024;
    const int region = (n0 + wn * 64) >> 10;                 // 0=q,1=k,2=v (wave-uniform)
    const int hh = ((n0 + wn * 64) & (DMODEL - 1)) >> 6;     // head
    unsigned short* dst = region == 0 ? qo : (region == 1 ? ko : vo);
    const float mul = region == 0 ? QSCALE : 1.0f;
    float bv[4];
    #pragma unroll
    for (int ni = 0; ni < 4; ++ni) bv[ni] = bias[n0 + wn * 64 + ni * 16 + lrow];
    const int r2 = lane >> 2, c2 = lane & 3;
    #pragma unroll
    for (int mi = 0; mi < 4; ++mi){
      #pragma unroll
      for (int ni = 0; ni < 4; ++ni)
        #pragma unroll
        for (int r_ = 0; r_ < 4; ++r_){
          const int row = (kseg << 2) + r_;
          const int col = (ni * 16 + lrow) ^ (kseg << 3);    // bank-spread swizzle
          Ls[row * 64 + col] = f2bf((acc[mi][ni][r_] + bv[ni]) * mul);
        }
      __syncthreads();
      const int grr = m0 + wm * 64 + mi * 16 + r2;
      const int bb = grr >> 11, tt = grr & (TSEQ - 1);
      unsigned short* drow = dst + (((size_t)bb * NHEAD + hh) * TSEQ + tt) * 64;
      #pragma unroll
      for (int half = 0; half < 2; ++half){
        const int d0 = c2 * 8 + half * 32;
        const int colb = d0 ^ ((r2 >> 2) << 3);
        *(bf16x8*)&drow[d0] = *(const bf16x8*)&Ls[r2 * 64 + colb];
      }
      __syncthreads();
    }
  }
}

// ---------------- causal flash attention, 32x32 swapped-QK^T structure ----------------
// V consumed in natural [BH][T][64] layout: reg-staged + LDS-transposed write with
// bijective element swizzle t' = t ^ (f(d)<<3), f(d) = ((d>>3)^d)&7.
__global__ __launch_bounds__(256, 2) void attn_kernel(
    const unsigned short* __restrict__ qg,   // [BH][T][64], pre-scaled by 0.125*log2e
    const unsigned short* __restrict__ kg,   // [BH][T][64]
    const unsigned short* __restrict__ vg,   // [BH][T][64]
    unsigned short* __restrict__ y)          // [B*T][1024] bf16
{
  __shared__ unsigned short Ks[2][64 * 64];  // [key][d], chunk c holds src chunk c^(key&7)
  __shared__ unsigned short Vs[2][64 * 64];  // [d][t'], t' = t ^ (f(d)<<3)

  const int nwg  = gridDim.x * gridDim.y;    // 512
  const int orig = blockIdx.y * gridDim.x + blockIdx.x;
  const int swz  = (orig & 7) * (nwg >> 3) + (orig >> 3);
  const int p  = swz & 7;
  const int bh = swz >> 3;
  const int bb = bh >> 4, h = bh & (NHEAD - 1);

  const int tid = threadIdx.x, lane = tid & 63, w = tid >> 6;
  const int l31 = lane & 31, hi = lane >> 5;
  const int sr8 = lane >> 3, sc8 = lane & 7;

  // V staging geometry: lane covers (t = w*16 + lane>>2, d0 = (lane&3)*8) and d0+32
  const int vt  = (w << 4) + (lane >> 2);
  const int vd0 = (lane & 3) << 3;

  auto issueK = [&](int buf, int kb){
    const int kt0 = kb * 64;
    #pragma unroll
    for (int j = 0; j < 2; ++j){
      const int idx = (w << 1) + j;
      const int r   = (idx << 3) + sr8;
      const int c8  = sc8 ^ (r & 7);
      gload_lds16(kg + ((size_t)bh * TSEQ + kt0 + r) * 64 + c8 * 8, &Ks[buf][idx * 512]);
    }
  };
  auto loadV = [&](int kb, bf16x8& va, bf16x8& vb){
    const unsigned short* src = vg + ((size_t)bh * TSEQ + kb * 64 + vt) * 64 + vd0;
    va = *(const bf16x8*)src;
    vb = *(const bf16x8*)(src + 32);
  };
  auto writeV = [&](int buf, bf16x8 va, bf16x8 vb){
    #pragma unroll
    for (int j = 0; j < 8; ++j){
      const int d1 = vd0 + j, d2 = vd0 + 32 + j;
      Vs[buf][d1 * 64 + (vt ^ ((((d1 >> 3) ^ d1) & 7) << 3))] = ((unsigned short*)&va)[j];
      Vs[buf][d2 * 64 + (vt ^ ((((d2 >> 3) ^ d2) & 7) << 3))] = ((unsigned short*)&vb)[j];
    }
  };

  int cur = 0;
  for (int hf = 0; hf < 2; ++hf){
    const int qt  = hf ? (15 - p) : p;
    const int q0w = qt * 128 + w * 32;
    const int q   = q0w + l31;
    const int nkv = 2 * qt + 2;

    bf16x8 qf[4];
    {
      const unsigned short* qp = qg + ((size_t)bh * TSEQ + q) * 64 + hi * 8;
      #pragma unroll
      for (int dk = 0; dk < 4; ++dk) qf[dk] = *(const bf16x8*)(qp + dk * 16);
    }

    f32x16 o0 = {}, o1 = {};
    float m_run = -1e30f, l_run = 0.f;

    {  // prologue: stage tile 0
      bf16x8 va, vb;
      issueK(cur, 0);
      loadV(0, va, vb);
      asm volatile("s_waitcnt vmcnt(0)" ::: "memory");
      writeV(cur, va, vb);
    }
    __syncthreads();

    for (int kb = 0; kb < nkv; ++kb){
      const int kt0 = kb * 64;
      bf16x8 va, vb;
      const bool pre = (kb + 1 < nkv);
      if (pre){ issueK(cur ^ 1, kb + 1); loadV(kb + 1, va, vb); }

      if (kt0 <= q0w + 31){
        // ---- S^T = K Q^T ----
        f32x16 s0 = {}, s1 = {};
        #pragma unroll
        for (int dk = 0; dk < 4; ++dk){
          const int c = ((dk << 1) + hi) ^ (l31 & 7);
          bf16x8 k0 = *(const bf16x8*)&Ks[cur][ l31       * 64 + c * 8];
          bf16x8 k1 = *(const bf16x8*)&Ks[cur][(l31 + 32) * 64 + c * 8];
          s0 = mfma32(k0, qf[dk], s0);
          s1 = mfma32(k1, qf[dk], s1);
        }
        if (kt0 + 63 > q0w){
          #pragma unroll
          for (int r = 0; r < 16; ++r){
            const int key = kt0 + (r & 3) + 8 * (r >> 2) + 4 * hi;
            if (key      > q) s0[r] = -1e30f;
            if (key + 32 > q) s1[r] = -1e30f;
          }
        }
        // ---- lane-local softmax ----
        float t16[16];
        #pragma unroll
        for (int i = 0; i < 16; ++i) t16[i] = fmaxf(s0[i], s1[i]);
        #pragma unroll
        for (int st = 8; st >= 1; st >>= 1)
          #pragma unroll
          for (int i = 0; i < 16; ++i) if (i < st) t16[i] = fmaxf(t16[i], t16[i + st]);
        float mx = fmaxf(t16[0], __shfl_xor(t16[0], 32));
        const float mnew = fmaxf(m_run, mx);
        const float resc = __builtin_amdgcn_exp2f(m_run - mnew);
        m_run = mnew;
        float sa = 0.f, sb = 0.f, sc_ = 0.f, sd = 0.f;
        #pragma unroll
        for (int i = 0; i < 4; ++i){
          s0[i]      = __builtin_amdgcn_exp2f(s0[i]      - mnew); sa += s0[i];
          s0[i + 4]  = __builtin_amdgcn_exp2f(s0[i + 4]  - mnew); sb += s0[i + 4];
          s0[i + 8]  = __builtin_amdgcn_exp2f(s0[i + 8]  - mnew); sc_ += s0[i + 8];
          s0[i + 12] = __builtin_amdgcn_exp2f(s0[i + 12] - mnew); sd += s0[i + 12];
          s1[i]      = __builtin_amdgcn_exp2f(s1[i]      - mnew); sa += s1[i];
          s1[i + 4]  = __builtin_amdgcn_exp2f(s1[i + 4]  - mnew); sb += s1[i + 4];
          s1[i + 8]  = __builtin_amdgcn_exp2f(s1[i + 8]  - mnew); sc_ += s1[i + 8];
          s1[i + 12] = __builtin_amdgcn_exp2f(s1[i + 12] - mnew); sd += s1[i + 12];
        }
        float sum = (sa + sb) + (sc_ + sd);
        sum += __shfl_xor(sum, 32);
        l_run = l_run * resc + sum;
        #pragma unroll
        for (int r = 0; r < 16; ++r){ o0[r] *= resc; o1[r] *= resc; }
        // ---- pack P -> bf16 fragments ----
        bf16x8 pf[4];
        #pragma unroll
        for (int kc = 0; kc < 4; ++kc){
          const int base = (kc & 1) * 8;
          float p0,p1,p2,p3,p4,p5,p6,p7;
          if (kc < 2){ p0=s0[base];p1=s0[base+1];p2=s0[base+2];p3=s0[base+3];
                       p4=s0[base+4];p5=s0[base+5];p6=s0[base+6];p7=s0[base+7]; }
          else       { p0=s1[base];p1=s1[base+1];p2=s1[base+2];p3=s1[base+3];
                       p4=s1[base+4];p5=s1[base+5];p6=s1[base+6];p7=s1[base+7]; }
          unsigned X0 = cvt_pk_bf16(p0, p1), X1 = cvt_pk_bf16(p2, p3);
          unsigned Y0 = cvt_pk_bf16(p4, p5), Y1 = cvt_pk_bf16(p6, p7);
          auto sA = __builtin_amdgcn_permlane32_swap(X0, Y0, false, false);
          auto sB = __builtin_amdgcn_permlane32_swap(X1, Y1, false, false);
          union { unsigned u[4]; bf16x8 v; } fr;
          fr.u[0] = sA[0]; fr.u[1] = sB[0]; fr.u[2] = sA[1]; fr.u[3] = sB[1];
          pf[kc] = fr.v;
        }
        // ---- O += V^T P : read transposed-swizzled Vs ----
        const int fv0 = ((l31 >> 3) ^ l31) & 7;     // f(d) for d = l31
        const int fv1 = fv0 ^ 4;                    // f(d+32)
        #pragma unroll
        for (int kc = 0; kc < 4; ++kc){
          const int tc = (kc << 1) + hi;
          bf16x8 v0 = *(const bf16x8*)&Vs[cur][ l31       * 64 + ((tc ^ fv0) << 3)];
          bf16x8 v1 = *(const bf16x8*)&Vs[cur][(l31 + 32) * 64 + ((tc ^ fv1) << 3)];
          o0 = mfma32(v0, pf[kc], o0);
          o1 = mfma32(v1, pf[kc], o1);
        }
      }

      if (pre){
        asm volatile("s_waitcnt vmcnt(0)" ::: "memory");   // V regs + K gloads landed
        writeV(cur ^ 1, va, vb);
      }
      __syncthreads();
      cur ^= 1;
    }

    // ---- epilogue ----
    const float rl = 1.0f / l_run;
    unsigned short* yrow = y + ((size_t)bb * TSEQ + q) * DMODEL + h * 64;
    #pragma unroll
    for (int i = 0; i < 8; ++i){
      const int r = 2 * i;
      const int d = (r & 3) + 8 * (r >> 2) + 4 * hi;
      unsigned pk0 = (unsigned)f2bf(o0[r] * rl) | ((unsigned)f2bf(o0[r + 1] * rl) << 16);
      unsigned pk1 = (unsigned)f2bf(o1[r] * rl) | ((unsigned)f2bf(o1[r + 1] * rl) << 16);
      *(unsigned*)(yrow + d)      = pk0;
      *(unsigned*)(yrow + d + 32) = pk1;
    }
  }
}

extern "C" void kernel_launch(void* const* d_in, const int* in_sizes, int n_in,
                              void* d_out, int out_size, void* d_ws, size_t ws_size,
                              hipStream_t stream) {
  const float* x    = (const float*)d_in[0];
  const float* Wqkv = (const float*)d_in[1];
  const float* bqkv = (const float*)d_in[2];
  const float* Wo   = (const float*)d_in[3];
  const float* bo   = (const float*)d_in[4];
  float* out = (float*)d_out;

  char* ws = (char*)d_ws;
  unsigned short* x_bf   = (unsigned short*)(ws);
  unsigned short* Wqkv_t = (unsigned short*)(ws + (16u << 20));
  unsigned short* Wo_t   = (unsigned short*)(ws + (22u << 20));
  unsigned short* q_ws   = (unsigned short*)(ws + (24u << 20));
  unsigned short* k_ws   = (unsigned short*)(ws + (40u << 20));
  unsigned short* v_ws   = (unsigned short*)(ws + (56u << 20));
  unsigned short* y_bf   = x_bf;   // x_bf dead after GEMM1

  cast_x_kernel<<<8192, 256, 0, stream>>>(x, x_bf);
  transpose_cast_kernel<<<dim3(96, 32), 256, 0, stream>>>(Wqkv, Wqkv_t, 1024, 3072);
  transpose_cast_kernel<<<dim3(32, 32), 256, 0, stream>>>(Wo, Wo_t, 1024, 1024);

  gemm_bf16_kernel<0><<<dim3(12, 64), 512, 0, stream>>>(x_bf, Wqkv_t, bqkv,
                                                        nullptr, q_ws, k_ws, v_ws, 1024, 3072);
  attn_kernel<<<dim3(8, 64), 256, 0, stream>>>(q_ws, k_ws, v_ws, y_bf);
  gemm_bf16_kernel<1><<<dim3(4, 64), 512, 0, stream>>>(y_bf, Wo_t, bo,
                                                       out, nullptr, nullptr, nullptr, 1024, 1024);
}